// Round 1
// baseline (863.851 us; speedup 1.0000x reference)
//
#include <hip/hip_runtime.h>

#define NS 512
#define DF 512
#define NQ 16384

// ws layout (float offsets)
#define WS_MEAN0 0
#define WS_MEAN1 512
#define WS_MEANA 1024
#define WS_CNT   1536
#define WS_V0    2048
#define WS_V1    2560
#define WS_KC    3072
#define WS_M     4096   // Mbuf [2][512][512] fp32

// ---------------- K1: class stats ----------------
__global__ __launch_bounds__(256) void k_stats(const float* __restrict__ S,
                                               const int* __restrict__ lab,
                                               float* __restrict__ ws) {
    __shared__ int lb[NS];
    int tid = threadIdx.x;
    for (int l = tid; l < NS; l += 256) lb[l] = lab[l];
    __syncthreads();
    int dd = blockIdx.x * 256 + tid;
    float s0 = 0.f, s1 = 0.f;
    int n1 = 0;
    for (int n = 0; n < NS; ++n) {
        float v = S[n * DF + dd];
        if (lb[n]) { s1 += v; n1++; } else { s0 += v; }
    }
    float fn1 = (float)n1;
    float fn0 = (float)(NS - n1);
    ws[WS_MEAN0 + dd] = s0 / fn0;
    ws[WS_MEAN1 + dd] = s1 / fn1;
    ws[WS_MEANA + dd] = (s0 + s1) / (float)NS;
    if (dd == 0) { ws[WS_CNT] = fn0; ws[WS_CNT + 1] = fn1; }
}

// ---------------- K2: masked Gram + assemble M_c ----------------
__global__ __launch_bounds__(256) void k_gram(const float* __restrict__ S,
                                              const int* __restrict__ lab,
                                              float* __restrict__ ws) {
    __shared__ float SA[16 * 65];
    __shared__ float SB[16 * 65];
    __shared__ int lb[16];
    int tx = threadIdx.x, ty = threadIdx.y;
    int tid = ty * 16 + tx;
    int i0 = blockIdx.x * 64, j0 = blockIdx.y * 64;
    float a0[4][4] = {{0.f}}, a1[4][4] = {{0.f}};
    for (int nc = 0; nc < NS; nc += 16) {
#pragma unroll
        for (int l = 0; l < 4; ++l) {
            int idx = tid + 256 * l;
            int nn = idx >> 6, col = idx & 63;
            SA[nn * 65 + col] = S[(nc + nn) * DF + i0 + col];
            SB[nn * 65 + col] = S[(nc + nn) * DF + j0 + col];
        }
        if (tid < 16) lb[tid] = lab[nc + tid];
        __syncthreads();
#pragma unroll
        for (int kk = 0; kk < 16; ++kk) {
            float av[4], bv[4];
#pragma unroll
            for (int r = 0; r < 4; ++r) av[r] = SA[kk * 65 + ty * 4 + r];
#pragma unroll
            for (int s = 0; s < 4; ++s) bv[s] = SB[kk * 65 + tx * 4 + s];
            if (lb[kk]) {
#pragma unroll
                for (int r = 0; r < 4; ++r)
#pragma unroll
                    for (int s = 0; s < 4; ++s) a1[r][s] += av[r] * bv[s];
            } else {
#pragma unroll
                for (int r = 0; r < 4; ++r)
#pragma unroll
                    for (int s = 0; s < 4; ++s) a0[r][s] += av[r] * bv[s];
            }
        }
        __syncthreads();
    }
    float n0 = ws[WS_CNT], n1 = ws[WS_CNT + 1];
    float lam0 = fminf(n0 / (n0 + 1.f), 0.1f);
    float lam1 = fminf(n1 / (n1 + 1.f), 0.1f);
    float* M0 = ws + WS_M;
    float* M1 = ws + WS_M + DF * DF;
#pragma unroll
    for (int r = 0; r < 4; ++r) {
        int i = i0 + ty * 4 + r;
        float m0i = ws[WS_MEAN0 + i], m1i = ws[WS_MEAN1 + i], mai = ws[WS_MEANA + i];
#pragma unroll
        for (int s = 0; s < 4; ++s) {
            int j = j0 + tx * 4 + s;
            float m0j = ws[WS_MEAN0 + j], m1j = ws[WS_MEAN1 + j], maj = ws[WS_MEANA + j];
            float G0 = a0[r][s], G1 = a1[r][s];
            float task = (G0 + G1 - (float)NS * mai * maj) / (float)(NS - 1);
            float cov0 = (G0 - n0 * m0i * m0j) / (n0 - 1.f);
            float cov1 = (G1 - n1 * m1i * m1j) / (n1 - 1.f);
            float dg = (i == j) ? 0.1f : 0.f;
            M0[i * DF + j] = lam0 * cov0 + (1.f - lam0) * task + dg;
            M1[i * DF + j] = lam1 * cov1 + (1.f - lam1) * task + dg;
        }
    }
}

// ---------------- K3: blocked Gauss-Jordan inversion (in place) ----------------
// step k: P = inv(Akk) in place; row-scale A[k][j]=P*A[k][j]; outer A[i][j]-=A[i][k]*A[k][j];
//         col-scale A[i][k] = -A[i][k]*P.   (SPD => no pivoting needed)

__global__ __launch_bounds__(512) void k_inv64(float* __restrict__ ws, int k) {
    int c = blockIdx.x;
    float* A = ws + WS_M + c * DF * DF + (k * 64) * DF + k * 64;
    __shared__ float T[64 * 65];
    int tid = threadIdx.x;  // 512 threads
#pragma unroll
    for (int m = 0; m < 8; ++m) {
        int idx = tid + 512 * m;
        int i = idx >> 6, j = idx & 63;
        T[i * 65 + j] = A[i * DF + j];
    }
    __syncthreads();
    int j = tid & 63;
    int i0 = tid >> 6;
    for (int p = 0; p < 64; ++p) {
        float piv = 1.0f / T[p * 65 + p];
        float apj = T[p * 65 + j];
        float sc = apj * piv;   // new row-p value for column j
        float aip[8], oldv[8];
#pragma unroll
        for (int m = 0; m < 8; ++m) {
            int i = i0 + 8 * m;
            aip[m] = T[i * 65 + p];
            oldv[m] = T[i * 65 + j];
        }
        __syncthreads();
#pragma unroll
        for (int m = 0; m < 8; ++m) {
            int i = i0 + 8 * m;
            float nv;
            if (i == p) nv = (j == p) ? piv : sc;
            else if (j == p) nv = -aip[m] * piv;
            else nv = oldv[m] - aip[m] * sc;
            T[i * 65 + j] = nv;
        }
        __syncthreads();
    }
#pragma unroll
    for (int m = 0; m < 8; ++m) {
        int idx = tid + 512 * m;
        int i = idx >> 6, jj = idx & 63;
        A[i * DF + jj] = T[i * 65 + jj];
    }
}

__global__ __launch_bounds__(256) void k_rowscale(float* __restrict__ ws, int k) {
    int c = blockIdx.y;
    int jt = blockIdx.x;
    int j = jt + (jt >= k ? 1 : 0);
    float* Mb = ws + WS_M + c * DF * DF;
    const float* P = Mb + (k * 64) * DF + k * 64;
    float* X = Mb + (k * 64) * DF + j * 64;
    __shared__ float Pl[64 * 65];
    __shared__ float Xl[64 * 65];
    int tx = threadIdx.x, ty = threadIdx.y, tid = ty * 16 + tx;
    for (int l = 0; l < 16; ++l) {
        int idx = tid + 256 * l;
        int ii = idx >> 6, jj = idx & 63;
        Pl[ii * 65 + jj] = P[ii * DF + jj];
        Xl[ii * 65 + jj] = X[ii * DF + jj];
    }
    __syncthreads();
    float acc[4][4] = {{0.f}};
    for (int kk = 0; kk < 64; ++kk) {
        float av[4], bv[4];
#pragma unroll
        for (int r = 0; r < 4; ++r) av[r] = Pl[(ty * 4 + r) * 65 + kk];
#pragma unroll
        for (int s = 0; s < 4; ++s) bv[s] = Xl[kk * 65 + tx * 4 + s];
#pragma unroll
        for (int r = 0; r < 4; ++r)
#pragma unroll
            for (int s = 0; s < 4; ++s) acc[r][s] += av[r] * bv[s];
    }
#pragma unroll
    for (int r = 0; r < 4; ++r)
#pragma unroll
        for (int s = 0; s < 4; ++s)
            X[(ty * 4 + r) * DF + tx * 4 + s] = acc[r][s];
}

__global__ __launch_bounds__(256) void k_outer(float* __restrict__ ws, int k) {
    int c = blockIdx.y;
    int it = blockIdx.x / 7, jt = blockIdx.x % 7;
    int i = it + (it >= k ? 1 : 0);
    int j = jt + (jt >= k ? 1 : 0);
    float* Mb = ws + WS_M + c * DF * DF;
    const float* Ct = Mb + (i * 64) * DF + k * 64;  // A[i][k] (old)
    const float* Rt = Mb + (k * 64) * DF + j * 64;  // A[k][j] (new)
    float* Y = Mb + (i * 64) * DF + j * 64;
    __shared__ float Cl[64 * 65];
    __shared__ float Rl[64 * 65];
    int tx = threadIdx.x, ty = threadIdx.y, tid = ty * 16 + tx;
    for (int l = 0; l < 16; ++l) {
        int idx = tid + 256 * l;
        int ii = idx >> 6, jj = idx & 63;
        Cl[ii * 65 + jj] = Ct[ii * DF + jj];
        Rl[ii * 65 + jj] = Rt[ii * DF + jj];
    }
    __syncthreads();
    float acc[4][4] = {{0.f}};
    for (int kk = 0; kk < 64; ++kk) {
        float av[4], bv[4];
#pragma unroll
        for (int r = 0; r < 4; ++r) av[r] = Cl[(ty * 4 + r) * 65 + kk];
#pragma unroll
        for (int s = 0; s < 4; ++s) bv[s] = Rl[kk * 65 + tx * 4 + s];
#pragma unroll
        for (int r = 0; r < 4; ++r)
#pragma unroll
            for (int s = 0; s < 4; ++s) acc[r][s] += av[r] * bv[s];
    }
#pragma unroll
    for (int r = 0; r < 4; ++r)
#pragma unroll
        for (int s = 0; s < 4; ++s) {
            int off = (ty * 4 + r) * DF + tx * 4 + s;
            Y[off] = Y[off] - acc[r][s];
        }
}

__global__ __launch_bounds__(256) void k_colscale(float* __restrict__ ws, int k) {
    int c = blockIdx.y;
    int it = blockIdx.x;
    int i = it + (it >= k ? 1 : 0);
    float* Mb = ws + WS_M + c * DF * DF;
    const float* P = Mb + (k * 64) * DF + k * 64;
    float* X = Mb + (i * 64) * DF + k * 64;
    __shared__ float Pl[64 * 65];
    __shared__ float Xl[64 * 65];
    int tx = threadIdx.x, ty = threadIdx.y, tid = ty * 16 + tx;
    for (int l = 0; l < 16; ++l) {
        int idx = tid + 256 * l;
        int ii = idx >> 6, jj = idx & 63;
        Pl[ii * 65 + jj] = P[ii * DF + jj];
        Xl[ii * 65 + jj] = X[ii * DF + jj];
    }
    __syncthreads();
    float acc[4][4] = {{0.f}};
    for (int kk = 0; kk < 64; ++kk) {
        float av[4], bv[4];
#pragma unroll
        for (int r = 0; r < 4; ++r) av[r] = Xl[(ty * 4 + r) * 65 + kk];
#pragma unroll
        for (int s = 0; s < 4; ++s) bv[s] = Pl[kk * 65 + tx * 4 + s];
#pragma unroll
        for (int r = 0; r < 4; ++r)
#pragma unroll
            for (int s = 0; s < 4; ++s) acc[r][s] += av[r] * bv[s];
    }
#pragma unroll
    for (int r = 0; r < 4; ++r)
#pragma unroll
        for (int s = 0; s < 4; ++s)
            X[(ty * 4 + r) * DF + tx * 4 + s] = -acc[r][s];
}

// ---------------- K4: v_c = P_c m_c,  k_c = m_c^T v_c ----------------
__global__ __launch_bounds__(256) void k_vk(float* __restrict__ ws) {
    int c = blockIdx.x;
    const float* P = ws + WS_M + c * DF * DF;
    const float* mc = ws + (c ? WS_MEAN1 : WS_MEAN0);
    float* v = ws + (c ? WS_V1 : WS_V0);
    __shared__ float ml[DF];
    __shared__ float red[256];
    int tid = threadIdx.x;
    for (int l = tid; l < DF; l += 256) ml[l] = mc[l];
    __syncthreads();
    float kpart = 0.f;
    for (int e = tid; e < DF; e += 256) {
        float dot = 0.f;
        for (int d2 = 0; d2 < DF; ++d2) dot += P[e * DF + d2] * ml[d2];
        v[e] = dot;
        kpart += dot * ml[e];
    }
    red[tid] = kpart;
    __syncthreads();
    for (int off = 128; off > 0; off >>= 1) {
        if (tid < off) red[tid] += red[tid + off];
        __syncthreads();
    }
    if (tid == 0) ws[WS_KC + c] = red[0];
}

// ---------------- K5: logits init = 2 q.v_c - k_c ----------------
__global__ __launch_bounds__(256) void k_init(const float* __restrict__ Q,
                                              const float* __restrict__ ws,
                                              float* __restrict__ out) {
    int lane = threadIdx.x & 63;
    int q = blockIdx.x * 4 + (threadIdx.x >> 6);
    const float* v0 = ws + WS_V0;
    const float* v1 = ws + WS_V1;
    float a0 = 0.f, a1 = 0.f;
#pragma unroll
    for (int m = 0; m < 8; ++m) {
        int e = lane + 64 * m;
        float qv = Q[q * DF + e];
        a0 += qv * v0[e];
        a1 += qv * v1[e];
    }
#pragma unroll
    for (int off = 32; off > 0; off >>= 1) {
        a0 += __shfl_down(a0, off);
        a1 += __shfl_down(a1, off);
    }
    if (lane == 0) {
        out[q * 2 + 0] = 2.f * a0 - ws[WS_KC + 0];
        out[q * 2 + 1] = 2.f * a1 - ws[WS_KC + 1];
    }
}

// ---------------- K6: fused GEMM  (-= q^T P_c q) ----------------
__global__ __launch_bounds__(256) void k_gemm(const float* __restrict__ Q,
                                              const float* __restrict__ ws,
                                              float* __restrict__ out) {
    __shared__ __align__(16) float QA[16 * 132];
    __shared__ __align__(16) float PB[16 * 132];
    __shared__ float red[16 * 17];
    int tx = threadIdx.x, ty = threadIdx.y, tid = ty * 16 + tx;
    int q0 = blockIdx.x * 128;
    int jb = blockIdx.y;         // 0..7
    int c = jb >> 2;
    int jl0 = (jb & 3) * 128;
    const float* Pm = ws + WS_M + c * DF * DF;
    float acc[8][8] = {{0.f}};
    for (int kc = 0; kc < DF; kc += 16) {
#pragma unroll
        for (int l = 0; l < 2; ++l) {
            int idx4 = tid + 256 * l;            // 0..511
            int qi = idx4 >> 2;                  // 0..127
            int kq = (idx4 & 3) * 4;
            const float4 qv = *(const float4*)&Q[(q0 + qi) * DF + kc + kq];
            QA[(kq + 0) * 132 + qi] = qv.x;
            QA[(kq + 1) * 132 + qi] = qv.y;
            QA[(kq + 2) * 132 + qi] = qv.z;
            QA[(kq + 3) * 132 + qi] = qv.w;
            int kk = idx4 >> 5;                  // 0..15
            int jj4 = (idx4 & 31) * 4;
            *(float4*)&PB[kk * 132 + jj4] =
                *(const float4*)&Pm[(kc + kk) * DF + jl0 + jj4];
        }
        __syncthreads();
#pragma unroll
        for (int kk = 0; kk < 16; ++kk) {
            float av[8], bv[8];
            *(float4*)&av[0] = *(const float4*)&QA[kk * 132 + ty * 8];
            *(float4*)&av[4] = *(const float4*)&QA[kk * 132 + ty * 8 + 4];
            *(float4*)&bv[0] = *(const float4*)&PB[kk * 132 + tx * 8];
            *(float4*)&bv[4] = *(const float4*)&PB[kk * 132 + tx * 8 + 4];
#pragma unroll
            for (int r = 0; r < 8; ++r)
#pragma unroll
                for (int s = 0; s < 8; ++s) acc[r][s] += av[r] * bv[s];
        }
        __syncthreads();
    }
    // epilogue: partial row-dots of H with Q over this column tile
    float partial[8];
#pragma unroll
    for (int r = 0; r < 8; ++r) {
        int q = q0 + ty * 8 + r;
        float qv[8];
        *(float4*)&qv[0] = *(const float4*)&Q[q * DF + jl0 + tx * 8];
        *(float4*)&qv[4] = *(const float4*)&Q[q * DF + jl0 + tx * 8 + 4];
        float pp = 0.f;
#pragma unroll
        for (int s = 0; s < 8; ++s) pp += acc[r][s] * qv[s];
        partial[r] = pp;
    }
#pragma unroll
    for (int r = 0; r < 8; ++r) {
        red[ty * 17 + tx] = partial[r];
        __syncthreads();
        if (tx == 0) {
            float s = 0.f;
            for (int x = 0; x < 16; ++x) s += red[ty * 17 + x];
            atomicAdd(&out[(q0 + ty * 8 + r) * 2 + c], -s);
        }
        __syncthreads();
    }
}

extern "C" void kernel_launch(void* const* d_in, const int* in_sizes, int n_in,
                              void* d_out, int out_size, void* d_ws, size_t ws_size,
                              hipStream_t stream) {
    const float* S  = (const float*)d_in[0];
    const int* lab  = (const int*)d_in[1];
    const float* Q  = (const float*)d_in[2];
    float* out = (float*)d_out;
    float* ws = (float*)d_ws;

    k_stats<<<2, 256, 0, stream>>>(S, lab, ws);
    k_gram<<<dim3(8, 8), dim3(16, 16), 0, stream>>>(S, lab, ws);
    for (int k = 0; k < 8; ++k) {
        k_inv64<<<2, 512, 0, stream>>>(ws, k);
        k_rowscale<<<dim3(7, 2), dim3(16, 16), 0, stream>>>(ws, k);
        k_outer<<<dim3(49, 2), dim3(16, 16), 0, stream>>>(ws, k);
        k_colscale<<<dim3(7, 2), dim3(16, 16), 0, stream>>>(ws, k);
    }
    k_vk<<<2, 256, 0, stream>>>(ws);
    k_init<<<NQ / 4, 256, 0, stream>>>(Q, ws, out);
    k_gemm<<<dim3(NQ / 128, 8), dim3(16, 16), 0, stream>>>(Q, ws, out);
}

// Round 2
// 632.129 us; speedup vs baseline: 1.3666x; 1.3666x over previous
//
#include <hip/hip_runtime.h>

#define NS 512
#define DF 512
#define NQ 16384

// ws layout (float offsets)
#define WS_MEAN0 0
#define WS_MEAN1 512
#define WS_MEANA 1024
#define WS_CNT   1536
#define WS_V0    2048
#define WS_V1    2560
#define WS_KC    3072
#define WS_M     4096                      // M / P fp32 [2][512][512]
#define WS_PB    (WS_M + 2*DF*DF)          // P bf16 [2][512][512] (as ushort)
#define WS_QB    (WS_PB + DF*DF)           // Q bf16 [16384][512]  (as ushort)
// total floats = WS_QB + NQ*DF/2 = 790528 + 4194304  (~19.9 MB)

typedef __attribute__((ext_vector_type(8))) short short8;
typedef __attribute__((ext_vector_type(4))) float floatx4;

__device__ __forceinline__ unsigned short f2bf(float f) {
    unsigned u = __float_as_uint(f);
    unsigned r = (u + 0x7fffu + ((u >> 16) & 1u)) >> 16;
    return (unsigned short)r;
}

// ---------------- K1: class stats (8 blocks, n-chunked) ----------------
__global__ __launch_bounds__(256) void k_stats(const float* __restrict__ S,
                                               const int* __restrict__ lab,
                                               float* __restrict__ ws) {
    __shared__ int lb[NS];
    __shared__ float r0[4][64], r1[4][64];
    __shared__ int rc[4];
    int tid = threadIdx.x;
    for (int l = tid; l < NS; l += 256) lb[l] = lab[l];
    __syncthreads();
    int dl = tid & 63, ch = tid >> 6;
    int dd = blockIdx.x * 64 + dl;
    float s0 = 0.f, s1 = 0.f;
    int n1 = 0;
    for (int n = ch * 128; n < ch * 128 + 128; ++n) {
        float v = S[n * DF + dd];
        if (lb[n]) { s1 += v; n1++; } else { s0 += v; }
    }
    r0[ch][dl] = s0; r1[ch][dl] = s1;
    if (dl == 0) rc[ch] = n1;
    __syncthreads();
    if (ch == 0) {
        float t0 = r0[0][dl] + r0[1][dl] + r0[2][dl] + r0[3][dl];
        float t1 = r1[0][dl] + r1[1][dl] + r1[2][dl] + r1[3][dl];
        int n1t = rc[0] + rc[1] + rc[2] + rc[3];
        float fn1 = (float)n1t, fn0 = (float)(NS - n1t);
        ws[WS_MEAN0 + dd] = t0 / fn0;
        ws[WS_MEAN1 + dd] = t1 / fn1;
        ws[WS_MEANA + dd] = (t0 + t1) / (float)NS;
        if (blockIdx.x == 0 && dl == 0) {
            ws[WS_CNT] = fn0; ws[WS_CNT + 1] = fn1;
            ws[WS_KC] = 0.f; ws[WS_KC + 1] = 0.f;
        }
    }
}

// ---------------- K2: masked Gram + assemble M_c ----------------
__global__ __launch_bounds__(256) void k_gram(const float* __restrict__ S,
                                              const int* __restrict__ lab,
                                              float* __restrict__ ws) {
    __shared__ float SA[16 * 65];
    __shared__ float SB[16 * 65];
    __shared__ int lb[16];
    int tx = threadIdx.x, ty = threadIdx.y;
    int tid = ty * 16 + tx;
    int i0 = blockIdx.x * 64, j0 = blockIdx.y * 64;
    float a0[4][4] = {{0.f}}, a1[4][4] = {{0.f}};
    for (int nc = 0; nc < NS; nc += 16) {
#pragma unroll
        for (int l = 0; l < 4; ++l) {
            int idx = tid + 256 * l;
            int nn = idx >> 6, col = idx & 63;
            SA[nn * 65 + col] = S[(nc + nn) * DF + i0 + col];
            SB[nn * 65 + col] = S[(nc + nn) * DF + j0 + col];
        }
        if (tid < 16) lb[tid] = lab[nc + tid];
        __syncthreads();
#pragma unroll
        for (int kk = 0; kk < 16; ++kk) {
            float av[4], bv[4];
#pragma unroll
            for (int r = 0; r < 4; ++r) av[r] = SA[kk * 65 + ty * 4 + r];
#pragma unroll
            for (int s = 0; s < 4; ++s) bv[s] = SB[kk * 65 + tx * 4 + s];
            if (lb[kk]) {
#pragma unroll
                for (int r = 0; r < 4; ++r)
#pragma unroll
                    for (int s = 0; s < 4; ++s) a1[r][s] += av[r] * bv[s];
            } else {
#pragma unroll
                for (int r = 0; r < 4; ++r)
#pragma unroll
                    for (int s = 0; s < 4; ++s) a0[r][s] += av[r] * bv[s];
            }
        }
        __syncthreads();
    }
    float n0 = ws[WS_CNT], n1 = ws[WS_CNT + 1];
    float lam0 = fminf(n0 / (n0 + 1.f), 0.1f);
    float lam1 = fminf(n1 / (n1 + 1.f), 0.1f);
    float* M0 = ws + WS_M;
    float* M1 = ws + WS_M + DF * DF;
#pragma unroll
    for (int r = 0; r < 4; ++r) {
        int i = i0 + ty * 4 + r;
        float m0i = ws[WS_MEAN0 + i], m1i = ws[WS_MEAN1 + i], mai = ws[WS_MEANA + i];
#pragma unroll
        for (int s = 0; s < 4; ++s) {
            int j = j0 + tx * 4 + s;
            float m0j = ws[WS_MEAN0 + j], m1j = ws[WS_MEAN1 + j], maj = ws[WS_MEANA + j];
            float G0 = a0[r][s], G1 = a1[r][s];
            float task = (G0 + G1 - (float)NS * mai * maj) / (float)(NS - 1);
            float cov0 = (G0 - n0 * m0i * m0j) / (n0 - 1.f);
            float cov1 = (G1 - n1 * m1i * m1j) / (n1 - 1.f);
            float dg = (i == j) ? 0.1f : 0.f;
            M0[i * DF + j] = lam0 * cov0 + (1.f - lam0) * task + dg;
            M1[i * DF + j] = lam1 * cov1 + (1.f - lam1) * task + dg;
        }
    }
}

// ---------------- K3: Q -> bf16 ----------------
__global__ __launch_bounds__(256) void k_qbf(const float* __restrict__ Q,
                                             float* __restrict__ ws) {
    unsigned short* qb = (unsigned short*)(ws + WS_QB);
    int idx = (blockIdx.x * 256 + threadIdx.x) * 16;
#pragma unroll
    for (int m = 0; m < 4; ++m) {
        float4 v = *(const float4*)(Q + idx + m * 4);
        ushort4 r;
        r.x = f2bf(v.x); r.y = f2bf(v.y); r.z = f2bf(v.z); r.w = f2bf(v.w);
        *(ushort4*)(qb + idx + m * 4) = r;
    }
}

// ---------------- K4: fused Gauss-Jordan step ----------------
// One launch per k. grid (64 tiles, 2 classes). Every block redundantly
// inverts the 64x64 pivot block in REGISTERS (1 barrier/pivot, parity-
// buffered row/col broadcasts), then applies its own tile update:
//   diag: Akk = P ; row: A[k][j] = P*U ; col: A[i][k] = -V*P ;
//   interior: A[i][j] -= V*(P*U).
// Reads of old tiles happen in phase 0 (first ~0.5us); first global write is
// after the ~4us inversion; 128 blocks < 256 CUs => co-resident, no hazard.
__global__ __launch_bounds__(256) void k_step(float* __restrict__ ws, int k, int wbf) {
    int c = blockIdx.y;
    int ti = blockIdx.x >> 3, tj = blockIdx.x & 7;
    float* Mb = ws + WS_M + c * DF * DF;
    float* Akk = Mb + (k * 64) * DF + k * 64;
    unsigned short* pb = (unsigned short*)(ws + WS_PB) + (size_t)c * DF * DF;
    __shared__ float T[64 * 65];
    __shared__ float LU[64 * 65];
    __shared__ float LV[64 * 65];
    __shared__ float rbuf[2][64];
    __shared__ float cbuf[2][64];
    int tid = threadIdx.x;
    int jl = tid & 63, w = tid >> 6;
    bool isdiag = (ti == k) && (tj == k);
    bool isrow = (ti == k) && (tj != k);
    bool iscol = (tj == k) && (ti != k);

    // phase 0: global reads (early)
#pragma unroll
    for (int m = 0; m < 16; ++m) {
        int idx = tid + 256 * m;
        int i = idx >> 6, j = idx & 63;
        T[i * 65 + j] = Akk[i * DF + j];
    }
    if (ti != k) {
        const float* src = Mb + (ti * 64) * DF + k * 64;   // V = A[ti][k]
#pragma unroll
        for (int m = 0; m < 16; ++m) {
            int idx = tid + 256 * m;
            int i = idx >> 6, j = idx & 63;
            LV[i * 65 + j] = src[i * DF + j];
        }
    }
    if (tj != k) {
        const float* src = Mb + (k * 64) * DF + tj * 64;   // U = A[k][tj]
#pragma unroll
        for (int m = 0; m < 16; ++m) {
            int idx = tid + 256 * m;
            int i = idx >> 6, j = idx & 63;
            LU[i * 65 + j] = src[i * DF + j];
        }
    }
    __syncthreads();

    // phase 1: in-register GJ inversion of T (thread owns col jl, rows w*16+m)
    float Tr[16];
#pragma unroll
    for (int m = 0; m < 16; ++m) Tr[m] = T[(w * 16 + m) * 65 + jl];
    for (int p = 0; p < 64; ++p) {
        int par = p & 1;
        if (w == (p >> 4)) rbuf[par][jl] = Tr[p & 15];
        if (jl == p) {
#pragma unroll
            for (int m = 0; m < 16; ++m) cbuf[par][w * 16 + m] = Tr[m];
        }
        __syncthreads();
        float rv = rbuf[par][jl];
        float piv = 1.0f / rbuf[par][p];
        float rvp = rv * piv;
#pragma unroll
        for (int m = 0; m < 16; ++m) {
            int i = w * 16 + m;
            float cv = cbuf[par][i];
            float nv = Tr[m] - cv * rvp;
            if (i == p) nv = rvp;
            if (jl == p) nv = -cv * piv;
            if (i == p && jl == p) nv = piv;
            Tr[m] = nv;
        }
    }
#pragma unroll
    for (int m = 0; m < 16; ++m) T[(w * 16 + m) * 65 + jl] = Tr[m];
    __syncthreads();

    // phase 2: tile update
    int tx = tid & 15, ty = tid >> 4;
    if (isdiag) {
#pragma unroll
        for (int m = 0; m < 16; ++m) {
            int idx = tid + 256 * m;
            int i = idx >> 6, j = idx & 63;
            float v = T[i * 65 + j];
            Akk[i * DF + j] = v;
            if (wbf) pb[(size_t)(k * 64 + i) * DF + k * 64 + j] = f2bf(v);
        }
    } else if (isrow) {
        float acc[4][4] = {{0.f}};
        for (int kk = 0; kk < 64; ++kk) {
            float av[4], bv[4];
#pragma unroll
            for (int r = 0; r < 4; ++r) av[r] = T[(ty * 4 + r) * 65 + kk];
#pragma unroll
            for (int s = 0; s < 4; ++s) bv[s] = LU[kk * 65 + tx * 4 + s];
#pragma unroll
            for (int r = 0; r < 4; ++r)
#pragma unroll
                for (int s = 0; s < 4; ++s) acc[r][s] += av[r] * bv[s];
        }
        float* dst = Mb + (k * 64) * DF + tj * 64;
#pragma unroll
        for (int r = 0; r < 4; ++r)
#pragma unroll
            for (int s = 0; s < 4; ++s) {
                float v = acc[r][s];
                dst[(ty * 4 + r) * DF + tx * 4 + s] = v;
                if (wbf) pb[(size_t)(k * 64 + ty * 4 + r) * DF + tj * 64 + tx * 4 + s] = f2bf(v);
            }
    } else if (iscol) {
        float acc[4][4] = {{0.f}};
        for (int kk = 0; kk < 64; ++kk) {
            float av[4], bv[4];
#pragma unroll
            for (int r = 0; r < 4; ++r) av[r] = LV[(ty * 4 + r) * 65 + kk];
#pragma unroll
            for (int s = 0; s < 4; ++s) bv[s] = T[kk * 65 + tx * 4 + s];
#pragma unroll
            for (int r = 0; r < 4; ++r)
#pragma unroll
                for (int s = 0; s < 4; ++s) acc[r][s] += av[r] * bv[s];
        }
        float* dst = Mb + (ti * 64) * DF + k * 64;
#pragma unroll
        for (int r = 0; r < 4; ++r)
#pragma unroll
            for (int s = 0; s < 4; ++s) {
                float v = -acc[r][s];
                dst[(ty * 4 + r) * DF + tx * 4 + s] = v;
                if (wbf) pb[(size_t)(ti * 64 + ty * 4 + r) * DF + k * 64 + tx * 4 + s] = f2bf(v);
            }
    } else {
        // D1 = P*U
        float a1[4][4] = {{0.f}};
        for (int kk = 0; kk < 64; ++kk) {
            float av[4], bv[4];
#pragma unroll
            for (int r = 0; r < 4; ++r) av[r] = T[(ty * 4 + r) * 65 + kk];
#pragma unroll
            for (int s = 0; s < 4; ++s) bv[s] = LU[kk * 65 + tx * 4 + s];
#pragma unroll
            for (int r = 0; r < 4; ++r)
#pragma unroll
                for (int s = 0; s < 4; ++s) a1[r][s] += av[r] * bv[s];
        }
        __syncthreads();
#pragma unroll
        for (int r = 0; r < 4; ++r)
#pragma unroll
            for (int s = 0; s < 4; ++s) LU[(ty * 4 + r) * 65 + tx * 4 + s] = a1[r][s];
        __syncthreads();
        // acc2 = V*D1 ; Y -= acc2
        float a2[4][4] = {{0.f}};
        for (int kk = 0; kk < 64; ++kk) {
            float av[4], bv[4];
#pragma unroll
            for (int r = 0; r < 4; ++r) av[r] = LV[(ty * 4 + r) * 65 + kk];
#pragma unroll
            for (int s = 0; s < 4; ++s) bv[s] = LU[kk * 65 + tx * 4 + s];
#pragma unroll
            for (int r = 0; r < 4; ++r)
#pragma unroll
                for (int s = 0; s < 4; ++s) a2[r][s] += av[r] * bv[s];
        }
        float* dst = Mb + (ti * 64) * DF + tj * 64;
#pragma unroll
        for (int r = 0; r < 4; ++r)
#pragma unroll
            for (int s = 0; s < 4; ++s) {
                int off = (ty * 4 + r) * DF + tx * 4 + s;
                float nv = dst[off] - a2[r][s];
                dst[off] = nv;
                if (wbf) pb[(size_t)(ti * 64 + ty * 4 + r) * DF + tj * 64 + tx * 4 + s] = f2bf(nv);
            }
    }
}

// ---------------- K5: v_c = P_c m_c, k_c = m^T v (16 blocks) ----------------
__global__ __launch_bounds__(256) void k_vk(float* __restrict__ ws) {
    int c = blockIdx.x >> 3, rb = blockIdx.x & 7;
    const float* P = ws + WS_M + c * DF * DF;
    const float* mc = ws + (c ? WS_MEAN1 : WS_MEAN0);
    float* v = ws + (c ? WS_V1 : WS_V0);
    __shared__ float ml[DF];
    __shared__ float red[4][64];
    int tid = threadIdx.x;
    for (int l = tid; l < DF; l += 256) ml[l] = mc[l];
    __syncthreads();
    int rl = tid & 63, ch = tid >> 6;
    int row = rb * 64 + rl;
    float dot = 0.f;
    const float* pr = P + (size_t)row * DF + ch * 128;
    for (int t = 0; t < 32; ++t) {
        float4 pv = *(const float4*)(pr + t * 4);
        const float* mm = ml + ch * 128 + t * 4;
        dot += pv.x * mm[0] + pv.y * mm[1] + pv.z * mm[2] + pv.w * mm[3];
    }
    red[ch][rl] = dot;
    __syncthreads();
    if (ch == 0) {
        float d = red[0][rl] + red[1][rl] + red[2][rl] + red[3][rl];
        v[row] = d;
        float kp = d * ml[row];
#pragma unroll
        for (int off = 32; off > 0; off >>= 1) kp += __shfl_down(kp, off);
        if (rl == 0) atomicAdd(&ws[WS_KC + c], kp);
    }
}

// ---------------- K6: logits init = 2 q.v_c - k_c ----------------
__global__ __launch_bounds__(256) void k_init(const float* __restrict__ Q,
                                              const float* __restrict__ ws,
                                              float* __restrict__ out) {
    int lane = threadIdx.x & 63;
    int q = blockIdx.x * 4 + (threadIdx.x >> 6);
    const float* v0 = ws + WS_V0;
    const float* v1 = ws + WS_V1;
    float a0 = 0.f, a1 = 0.f;
#pragma unroll
    for (int m = 0; m < 8; ++m) {
        int e = lane + 64 * m;
        float qv = Q[q * DF + e];
        a0 += qv * v0[e];
        a1 += qv * v1[e];
    }
#pragma unroll
    for (int off = 32; off > 0; off >>= 1) {
        a0 += __shfl_down(a0, off);
        a1 += __shfl_down(a1, off);
    }
    if (lane == 0) {
        out[q * 2 + 0] = 2.f * a0 - ws[WS_KC + 0];
        out[q * 2 + 1] = 2.f * a1 - ws[WS_KC + 1];
    }
}

// ---------------- K7: MFMA GEMM + fused rowdot epilogue ----------------
// H = Qbf * P_c (bf16, P symmetric: B[k][n] = Pbf[n][k]); out[q][c] -= sum_n H[q][n]*Q[q][n]
__global__ __launch_bounds__(256) void k_gemm(const float* __restrict__ ws,
                                              float* __restrict__ out) {
    const unsigned short* qb = (const unsigned short*)(ws + WS_QB);
    int c = blockIdx.y >> 2;
    int n0 = (blockIdx.y & 3) * 128;
    const unsigned short* pbc = (const unsigned short*)(ws + WS_PB) + (size_t)c * DF * DF;
    int q0 = blockIdx.x * 128;
    int tid = threadIdx.x;
    int w = tid >> 6, lane = tid & 63;
    int quad = lane >> 4, l15 = lane & 15;
    floatx4 acc[2][8];
#pragma unroll
    for (int mt = 0; mt < 2; ++mt)
#pragma unroll
        for (int nt = 0; nt < 8; ++nt) acc[mt][nt] = (floatx4)(0.f);
    int arow = q0 + w * 32 + l15;
    int brow = n0 + l15;
    int koff = quad * 8;
    for (int kc = 0; kc < DF; kc += 32) {
        short8 a0 = *(const short8*)(qb + (size_t)arow * DF + kc + koff);
        short8 a1 = *(const short8*)(qb + (size_t)(arow + 16) * DF + kc + koff);
        short8 b[8];
#pragma unroll
        for (int nt = 0; nt < 8; ++nt)
            b[nt] = *(const short8*)(pbc + (size_t)(brow + nt * 16) * DF + kc + koff);
#pragma unroll
        for (int nt = 0; nt < 8; ++nt) {
            acc[0][nt] = __builtin_amdgcn_mfma_f32_16x16x32_bf16(a0, b[nt], acc[0][nt], 0, 0, 0);
            acc[1][nt] = __builtin_amdgcn_mfma_f32_16x16x32_bf16(a1, b[nt], acc[1][nt], 0, 0, 0);
        }
    }
    // epilogue: partial row-dot with Q over this 128-col tile
#pragma unroll
    for (int mt = 0; mt < 2; ++mt)
#pragma unroll
        for (int reg = 0; reg < 4; ++reg) {
            int row = w * 32 + mt * 16 + quad * 4 + reg;
            float part = 0.f;
#pragma unroll
            for (int nt = 0; nt < 8; ++nt) {
                float h = acc[mt][nt][reg];
                unsigned qu = qb[(size_t)(q0 + row) * DF + n0 + nt * 16 + l15];
                part += h * __uint_as_float(qu << 16);
            }
            part += __shfl_xor(part, 1);
            part += __shfl_xor(part, 2);
            part += __shfl_xor(part, 4);
            part += __shfl_xor(part, 8);
            if (l15 == 0) atomicAdd(&out[(size_t)(q0 + row) * 2 + c], -part);
        }
}

extern "C" void kernel_launch(void* const* d_in, const int* in_sizes, int n_in,
                              void* d_out, int out_size, void* d_ws, size_t ws_size,
                              hipStream_t stream) {
    const float* S = (const float*)d_in[0];
    const int* lab = (const int*)d_in[1];
    const float* Q = (const float*)d_in[2];
    float* out = (float*)d_out;
    float* ws = (float*)d_ws;

    k_stats<<<8, 256, 0, stream>>>(S, lab, ws);
    k_gram<<<dim3(8, 8), dim3(16, 16), 0, stream>>>(S, lab, ws);
    k_qbf<<<2048, 256, 0, stream>>>(Q, ws);
    for (int k = 0; k < 8; ++k)
        k_step<<<dim3(64, 2), 256, 0, stream>>>(ws, k, k == 7 ? 1 : 0);
    k_vk<<<16, 256, 0, stream>>>(ws);
    k_init<<<NQ / 4, 256, 0, stream>>>(Q, ws, out);
    k_gemm<<<dim3(NQ / 128, 8), 256, 0, stream>>>(ws, out);
}

// Round 3
// 510.190 us; speedup vs baseline: 1.6932x; 1.2390x over previous
//
#include <hip/hip_runtime.h>

#define NS 512
#define DF 512
#define NQ 16384

// ws layout (float offsets)
#define WS_MEAN0 0
#define WS_MEAN1 512
#define WS_MEANA 1024
#define WS_CNT   1536
#define WS_V0    2048
#define WS_V1    2560
#define WS_KC    3072
#define WS_M     4096                      // M / P fp32 [2][512][512]
#define WS_PB    (WS_M + 2*DF*DF)          // P bf16 [2][512][512] (as ushort)
#define WS_QB    (WS_PB + DF*DF)           // Q bf16 [16384][512]  (as ushort)

typedef __attribute__((ext_vector_type(8))) short short8;
typedef __attribute__((ext_vector_type(4))) float floatx4;

__device__ __forceinline__ unsigned short f2bf(float f) {
    unsigned u = __float_as_uint(f);
    unsigned r = (u + 0x7fffu + ((u >> 16) & 1u)) >> 16;
    return (unsigned short)r;
}

// ---------------- K1: class stats (8 blocks, n-chunked) ----------------
__global__ __launch_bounds__(256) void k_stats(const float* __restrict__ S,
                                               const int* __restrict__ lab,
                                               float* __restrict__ ws) {
    __shared__ int lb[NS];
    __shared__ float r0[4][64], r1[4][64];
    __shared__ int rc[4];
    int tid = threadIdx.x;
    for (int l = tid; l < NS; l += 256) lb[l] = lab[l];
    __syncthreads();
    int dl = tid & 63, ch = tid >> 6;
    int dd = blockIdx.x * 64 + dl;
    float s0 = 0.f, s1 = 0.f;
    int n1 = 0;
    for (int n = ch * 128; n < ch * 128 + 128; ++n) {
        float v = S[n * DF + dd];
        if (lb[n]) { s1 += v; n1++; } else { s0 += v; }
    }
    r0[ch][dl] = s0; r1[ch][dl] = s1;
    if (dl == 0) rc[ch] = n1;
    __syncthreads();
    if (ch == 0) {
        float t0 = r0[0][dl] + r0[1][dl] + r0[2][dl] + r0[3][dl];
        float t1 = r1[0][dl] + r1[1][dl] + r1[2][dl] + r1[3][dl];
        int n1t = rc[0] + rc[1] + rc[2] + rc[3];
        float fn1 = (float)n1t, fn0 = (float)(NS - n1t);
        ws[WS_MEAN0 + dd] = t0 / fn0;
        ws[WS_MEAN1 + dd] = t1 / fn1;
        ws[WS_MEANA + dd] = (t0 + t1) / (float)NS;
        if (blockIdx.x == 0 && dl == 0) {
            ws[WS_CNT] = fn0; ws[WS_CNT + 1] = fn1;
            ws[WS_KC] = 0.f; ws[WS_KC + 1] = 0.f;
        }
    }
}

// ---------------- K2: masked Gram + assemble M_c ----------------
__global__ __launch_bounds__(256) void k_gram(const float* __restrict__ S,
                                              const int* __restrict__ lab,
                                              float* __restrict__ ws) {
    __shared__ float SA[16 * 65];
    __shared__ float SB[16 * 65];
    __shared__ int lb[16];
    int tx = threadIdx.x, ty = threadIdx.y;
    int tid = ty * 16 + tx;
    int i0 = blockIdx.x * 64, j0 = blockIdx.y * 64;
    float a0[4][4] = {{0.f}}, a1[4][4] = {{0.f}};
    for (int nc = 0; nc < NS; nc += 16) {
#pragma unroll
        for (int l = 0; l < 4; ++l) {
            int idx = tid + 256 * l;
            int nn = idx >> 6, col = idx & 63;
            SA[nn * 65 + col] = S[(nc + nn) * DF + i0 + col];
            SB[nn * 65 + col] = S[(nc + nn) * DF + j0 + col];
        }
        if (tid < 16) lb[tid] = lab[nc + tid];
        __syncthreads();
#pragma unroll
        for (int kk = 0; kk < 16; ++kk) {
            float av[4], bv[4];
#pragma unroll
            for (int r = 0; r < 4; ++r) av[r] = SA[kk * 65 + ty * 4 + r];
#pragma unroll
            for (int s = 0; s < 4; ++s) bv[s] = SB[kk * 65 + tx * 4 + s];
            if (lb[kk]) {
#pragma unroll
                for (int r = 0; r < 4; ++r)
#pragma unroll
                    for (int s = 0; s < 4; ++s) a1[r][s] += av[r] * bv[s];
            } else {
#pragma unroll
                for (int r = 0; r < 4; ++r)
#pragma unroll
                    for (int s = 0; s < 4; ++s) a0[r][s] += av[r] * bv[s];
            }
        }
        __syncthreads();
    }
    float n0 = ws[WS_CNT], n1 = ws[WS_CNT + 1];
    float lam0 = fminf(n0 / (n0 + 1.f), 0.1f);
    float lam1 = fminf(n1 / (n1 + 1.f), 0.1f);
    float* M0 = ws + WS_M;
    float* M1 = ws + WS_M + DF * DF;
#pragma unroll
    for (int r = 0; r < 4; ++r) {
        int i = i0 + ty * 4 + r;
        float m0i = ws[WS_MEAN0 + i], m1i = ws[WS_MEAN1 + i], mai = ws[WS_MEANA + i];
#pragma unroll
        for (int s = 0; s < 4; ++s) {
            int j = j0 + tx * 4 + s;
            float m0j = ws[WS_MEAN0 + j], m1j = ws[WS_MEAN1 + j], maj = ws[WS_MEANA + j];
            float G0 = a0[r][s], G1 = a1[r][s];
            float task = (G0 + G1 - (float)NS * mai * maj) / (float)(NS - 1);
            float cov0 = (G0 - n0 * m0i * m0j) / (n0 - 1.f);
            float cov1 = (G1 - n1 * m1i * m1j) / (n1 - 1.f);
            float dg = (i == j) ? 0.1f : 0.f;
            M0[i * DF + j] = lam0 * cov0 + (1.f - lam0) * task + dg;
            M1[i * DF + j] = lam1 * cov1 + (1.f - lam1) * task + dg;
        }
    }
}

// ---------------- K3: fused Gauss-Jordan step ----------------
// Pivot loop FULLY UNROLLED so Tr[] stays in VGPRs (dynamic index -> scratch
// spill was the R2 bug). One launch per k; every block redundantly inverts
// the 64x64 pivot block in registers, then applies its own tile update.
__global__ __launch_bounds__(256) void k_step(float* __restrict__ ws, int k, int wbf) {
    int c = blockIdx.y;
    int ti = blockIdx.x >> 3, tj = blockIdx.x & 7;
    float* Mb = ws + WS_M + c * DF * DF;
    float* Akk = Mb + (k * 64) * DF + k * 64;
    unsigned short* pb = (unsigned short*)(ws + WS_PB) + (size_t)c * DF * DF;
    __shared__ float T[64 * 65];
    __shared__ float LU[64 * 65];
    __shared__ float LV[64 * 65];
    __shared__ float rbuf[2][64];
    __shared__ float cbuf[2][64];
    int tid = threadIdx.x;
    int jl = tid & 63, w = tid >> 6;
    bool isdiag = (ti == k) && (tj == k);
    bool isrow = (ti == k) && (tj != k);
    bool iscol = (tj == k) && (ti != k);

    // phase 0: global reads (early)
#pragma unroll
    for (int m = 0; m < 16; ++m) {
        int idx = tid + 256 * m;
        int i = idx >> 6, j = idx & 63;
        T[i * 65 + j] = Akk[i * DF + j];
    }
    if (ti != k) {
        const float* src = Mb + (ti * 64) * DF + k * 64;   // V = A[ti][k]
#pragma unroll
        for (int m = 0; m < 16; ++m) {
            int idx = tid + 256 * m;
            int i = idx >> 6, j = idx & 63;
            LV[i * 65 + j] = src[i * DF + j];
        }
    }
    if (tj != k) {
        const float* src = Mb + (k * 64) * DF + tj * 64;   // U = A[k][tj]
#pragma unroll
        for (int m = 0; m < 16; ++m) {
            int idx = tid + 256 * m;
            int i = idx >> 6, j = idx & 63;
            LU[i * 65 + j] = src[i * DF + j];
        }
    }
    __syncthreads();

    // phase 1: in-register GJ inversion of T (thread owns col jl, rows w*16+m)
    float Tr[16];
#pragma unroll
    for (int m = 0; m < 16; ++m) Tr[m] = T[(w * 16 + m) * 65 + jl];
#pragma unroll
    for (int p = 0; p < 64; ++p) {
        const int par = p & 1;
        if (w == (p >> 4)) rbuf[par][jl] = Tr[p & 15];
        if (jl == p) {
#pragma unroll
            for (int m = 0; m < 16; ++m) cbuf[par][w * 16 + m] = Tr[m];
        }
        __syncthreads();
        float rv = rbuf[par][jl];
        float piv = 1.0f / rbuf[par][p];
        float rvp = rv * piv;
#pragma unroll
        for (int m = 0; m < 16; ++m) {
            int i = w * 16 + m;
            float cv = cbuf[par][i];
            float nv = Tr[m] - cv * rvp;
            if (i == p) nv = rvp;
            if (jl == p) nv = -cv * piv;
            if (i == p && jl == p) nv = piv;
            Tr[m] = nv;
        }
    }
#pragma unroll
    for (int m = 0; m < 16; ++m) T[(w * 16 + m) * 65 + jl] = Tr[m];
    __syncthreads();

    // phase 2: tile update
    int tx = tid & 15, ty = tid >> 4;
    if (isdiag) {
#pragma unroll
        for (int m = 0; m < 16; ++m) {
            int idx = tid + 256 * m;
            int i = idx >> 6, j = idx & 63;
            float v = T[i * 65 + j];
            Akk[i * DF + j] = v;
            if (wbf) pb[(size_t)(k * 64 + i) * DF + k * 64 + j] = f2bf(v);
        }
    } else if (isrow) {
        float acc[4][4] = {{0.f}};
        for (int kk = 0; kk < 64; ++kk) {
            float av[4], bv[4];
#pragma unroll
            for (int r = 0; r < 4; ++r) av[r] = T[(ty * 4 + r) * 65 + kk];
#pragma unroll
            for (int s = 0; s < 4; ++s) bv[s] = LU[kk * 65 + tx * 4 + s];
#pragma unroll
            for (int r = 0; r < 4; ++r)
#pragma unroll
                for (int s = 0; s < 4; ++s) acc[r][s] += av[r] * bv[s];
        }
        float* dst = Mb + (k * 64) * DF + tj * 64;
#pragma unroll
        for (int r = 0; r < 4; ++r)
#pragma unroll
            for (int s = 0; s < 4; ++s) {
                float v = acc[r][s];
                dst[(ty * 4 + r) * DF + tx * 4 + s] = v;
                if (wbf) pb[(size_t)(k * 64 + ty * 4 + r) * DF + tj * 64 + tx * 4 + s] = f2bf(v);
            }
    } else if (iscol) {
        float acc[4][4] = {{0.f}};
        for (int kk = 0; kk < 64; ++kk) {
            float av[4], bv[4];
#pragma unroll
            for (int r = 0; r < 4; ++r) av[r] = LV[(ty * 4 + r) * 65 + kk];
#pragma unroll
            for (int s = 0; s < 4; ++s) bv[s] = T[kk * 65 + tx * 4 + s];
#pragma unroll
            for (int r = 0; r < 4; ++r)
#pragma unroll
                for (int s = 0; s < 4; ++s) acc[r][s] += av[r] * bv[s];
        }
        float* dst = Mb + (ti * 64) * DF + k * 64;
#pragma unroll
        for (int r = 0; r < 4; ++r)
#pragma unroll
            for (int s = 0; s < 4; ++s) {
                float v = -acc[r][s];
                dst[(ty * 4 + r) * DF + tx * 4 + s] = v;
                if (wbf) pb[(size_t)(ti * 64 + ty * 4 + r) * DF + k * 64 + tx * 4 + s] = f2bf(v);
            }
    } else {
        // D1 = P*U
        float a1[4][4] = {{0.f}};
        for (int kk = 0; kk < 64; ++kk) {
            float av[4], bv[4];
#pragma unroll
            for (int r = 0; r < 4; ++r) av[r] = T[(ty * 4 + r) * 65 + kk];
#pragma unroll
            for (int s = 0; s < 4; ++s) bv[s] = LU[kk * 65 + tx * 4 + s];
#pragma unroll
            for (int r = 0; r < 4; ++r)
#pragma unroll
                for (int s = 0; s < 4; ++s) a1[r][s] += av[r] * bv[s];
        }
        __syncthreads();
#pragma unroll
        for (int r = 0; r < 4; ++r)
#pragma unroll
            for (int s = 0; s < 4; ++s) LU[(ty * 4 + r) * 65 + tx * 4 + s] = a1[r][s];
        __syncthreads();
        // acc2 = V*D1 ; Y -= acc2
        float a2[4][4] = {{0.f}};
        for (int kk = 0; kk < 64; ++kk) {
            float av[4], bv[4];
#pragma unroll
            for (int r = 0; r < 4; ++r) av[r] = LV[(ty * 4 + r) * 65 + kk];
#pragma unroll
            for (int s = 0; s < 4; ++s) bv[s] = LU[kk * 65 + tx * 4 + s];
#pragma unroll
            for (int r = 0; r < 4; ++r)
#pragma unroll
                for (int s = 0; s < 4; ++s) a2[r][s] += av[r] * bv[s];
        }
        float* dst = Mb + (ti * 64) * DF + tj * 64;
#pragma unroll
        for (int r = 0; r < 4; ++r)
#pragma unroll
            for (int s = 0; s < 4; ++s) {
                int off = (ty * 4 + r) * DF + tx * 4 + s;
                float nv = dst[off] - a2[r][s];
                dst[off] = nv;
                if (wbf) pb[(size_t)(ti * 64 + ty * 4 + r) * DF + tj * 64 + tx * 4 + s] = f2bf(nv);
            }
    }
}

// ---------------- K4: v_c = P_c m_c, k_c = m^T v (16 blocks) ----------------
__global__ __launch_bounds__(256) void k_vk(float* __restrict__ ws) {
    int c = blockIdx.x >> 3, rb = blockIdx.x & 7;
    const float* P = ws + WS_M + c * DF * DF;
    const float* mc = ws + (c ? WS_MEAN1 : WS_MEAN0);
    float* v = ws + (c ? WS_V1 : WS_V0);
    __shared__ float ml[DF];
    __shared__ float red[4][64];
    int tid = threadIdx.x;
    for (int l = tid; l < DF; l += 256) ml[l] = mc[l];
    __syncthreads();
    int rl = tid & 63, ch = tid >> 6;
    int row = rb * 64 + rl;
    float dot = 0.f;
    const float* pr = P + (size_t)row * DF + ch * 128;
    for (int t = 0; t < 32; ++t) {
        float4 pv = *(const float4*)(pr + t * 4);
        const float* mm = ml + ch * 128 + t * 4;
        dot += pv.x * mm[0] + pv.y * mm[1] + pv.z * mm[2] + pv.w * mm[3];
    }
    red[ch][rl] = dot;
    __syncthreads();
    if (ch == 0) {
        float d = red[0][rl] + red[1][rl] + red[2][rl] + red[3][rl];
        v[row] = d;
        float kp = d * ml[row];
#pragma unroll
        for (int off = 32; off > 0; off >>= 1) kp += __shfl_down(kp, off);
        if (rl == 0) atomicAdd(&ws[WS_KC + c], kp);
    }
}

// ---------------- K5: fused Q->bf16 + logits init (reads Q once) ----------------
__global__ __launch_bounds__(256) void k_qinit(const float* __restrict__ Q,
                                               float* __restrict__ ws,
                                               float* __restrict__ out) {
    unsigned short* qbw = (unsigned short*)(ws + WS_QB);
    const float* v0 = ws + WS_V0;
    const float* v1 = ws + WS_V1;
    int lane = threadIdx.x & 63;
    int q = blockIdx.x * 4 + (threadIdx.x >> 6);
    const float* qrow = Q + (size_t)q * DF + lane * 8;
    float4 x0 = *(const float4*)(qrow);
    float4 x1 = *(const float4*)(qrow + 4);
    const float* v0p = v0 + lane * 8;
    const float* v1p = v1 + lane * 8;
    float4 w00 = *(const float4*)(v0p), w01 = *(const float4*)(v0p + 4);
    float4 w10 = *(const float4*)(v1p), w11 = *(const float4*)(v1p + 4);
    float a0 = x0.x * w00.x + x0.y * w00.y + x0.z * w00.z + x0.w * w00.w
             + x1.x * w01.x + x1.y * w01.y + x1.z * w01.z + x1.w * w01.w;
    float a1 = x0.x * w10.x + x0.y * w10.y + x0.z * w10.z + x0.w * w10.w
             + x1.x * w11.x + x1.y * w11.y + x1.z * w11.z + x1.w * w11.w;
    short8 r;
    r[0] = (short)f2bf(x0.x); r[1] = (short)f2bf(x0.y);
    r[2] = (short)f2bf(x0.z); r[3] = (short)f2bf(x0.w);
    r[4] = (short)f2bf(x1.x); r[5] = (short)f2bf(x1.y);
    r[6] = (short)f2bf(x1.z); r[7] = (short)f2bf(x1.w);
    *(short8*)(qbw + (size_t)q * DF + lane * 8) = r;
#pragma unroll
    for (int off = 32; off > 0; off >>= 1) {
        a0 += __shfl_down(a0, off);
        a1 += __shfl_down(a1, off);
    }
    if (lane == 0) {
        out[q * 2 + 0] = 2.f * a0 - ws[WS_KC + 0];
        out[q * 2 + 1] = 2.f * a1 - ws[WS_KC + 1];
    }
}

// ---------------- K6: MFMA GEMM, 2-stage register pipeline ----------------
// H = Qbf * P_c (bf16, P symmetric); out[q][c] -= sum_n H[q][n]*Qbf[q][n]
__global__ __launch_bounds__(256, 2) void k_gemm(const float* __restrict__ ws,
                                                 float* __restrict__ out) {
    const unsigned short* qb = (const unsigned short*)(ws + WS_QB);
    int c = blockIdx.y >> 2;
    int n0 = (blockIdx.y & 3) * 128;
    const unsigned short* pbc = (const unsigned short*)(ws + WS_PB) + (size_t)c * DF * DF;
    int q0 = blockIdx.x * 128;
    int tid = threadIdx.x;
    int w = tid >> 6, lane = tid & 63;
    int quad = lane >> 4, l15 = lane & 15;
    floatx4 acc[2][8];
#pragma unroll
    for (int mt = 0; mt < 2; ++mt)
#pragma unroll
        for (int nt = 0; nt < 8; ++nt) acc[mt][nt] = (floatx4)(0.f);
    const unsigned short* aptr0 = qb + (size_t)(q0 + w * 32 + l15) * DF + quad * 8;
    const unsigned short* aptr1 = aptr0 + 16 * DF;
    const unsigned short* bptr = pbc + (size_t)(n0 + l15) * DF + quad * 8;

    short8 ca0 = *(const short8*)(aptr0);
    short8 ca1 = *(const short8*)(aptr1);
    short8 cb[8];
#pragma unroll
    for (int nt = 0; nt < 8; ++nt) cb[nt] = *(const short8*)(bptr + (size_t)nt * 16 * DF);

#pragma unroll
    for (int it = 0; it < 16; ++it) {
        short8 na0, na1, nb[8];
        if (it < 15) {
            int kc = (it + 1) * 32;
            na0 = *(const short8*)(aptr0 + kc);
            na1 = *(const short8*)(aptr1 + kc);
#pragma unroll
            for (int nt = 0; nt < 8; ++nt)
                nb[nt] = *(const short8*)(bptr + (size_t)nt * 16 * DF + kc);
        }
#pragma unroll
        for (int nt = 0; nt < 8; ++nt) {
            acc[0][nt] = __builtin_amdgcn_mfma_f32_16x16x32_bf16(ca0, cb[nt], acc[0][nt], 0, 0, 0);
            acc[1][nt] = __builtin_amdgcn_mfma_f32_16x16x32_bf16(ca1, cb[nt], acc[1][nt], 0, 0, 0);
        }
        if (it < 15) {
            ca0 = na0; ca1 = na1;
#pragma unroll
            for (int nt = 0; nt < 8; ++nt) cb[nt] = nb[nt];
        }
    }
    // epilogue: partial row-dot with Q over this 128-col tile
#pragma unroll
    for (int mt = 0; mt < 2; ++mt)
#pragma unroll
        for (int reg = 0; reg < 4; ++reg) {
            int row = w * 32 + mt * 16 + quad * 4 + reg;
            float part = 0.f;
#pragma unroll
            for (int nt = 0; nt < 8; ++nt) {
                float h = acc[mt][nt][reg];
                unsigned qu = qb[(size_t)(q0 + row) * DF + n0 + nt * 16 + l15];
                part += h * __uint_as_float(qu << 16);
            }
            part += __shfl_xor(part, 1);
            part += __shfl_xor(part, 2);
            part += __shfl_xor(part, 4);
            part += __shfl_xor(part, 8);
            if (l15 == 0) atomicAdd(&out[(size_t)(q0 + row) * 2 + c], -part);
        }
}

extern "C" void kernel_launch(void* const* d_in, const int* in_sizes, int n_in,
                              void* d_out, int out_size, void* d_ws, size_t ws_size,
                              hipStream_t stream) {
    const float* S = (const float*)d_in[0];
    const int* lab = (const int*)d_in[1];
    const float* Q = (const float*)d_in[2];
    float* out = (float*)d_out;
    float* ws = (float*)d_ws;

    k_stats<<<8, 256, 0, stream>>>(S, lab, ws);
    k_gram<<<dim3(8, 8), dim3(16, 16), 0, stream>>>(S, lab, ws);
    for (int k = 0; k < 8; ++k)
        k_step<<<dim3(64, 2), 256, 0, stream>>>(ws, k, k == 7 ? 1 : 0);
    k_vk<<<16, 256, 0, stream>>>(ws);
    k_qinit<<<NQ / 4, 256, 0, stream>>>(Q, ws, out);
    k_gemm<<<dim3(NQ / 128, 8), 256, 0, stream>>>(ws, out);
}

// Round 4
// 425.261 us; speedup vs baseline: 2.0313x; 1.1997x over previous
//
#include <hip/hip_runtime.h>

#define NS 512
#define DF 512
#define NQ 16384

// ws layout (float offsets)
#define WS_MEAN0 0
#define WS_MEAN1 512
#define WS_MEANA 1024
#define WS_CNT   1536
#define WS_V0    2048
#define WS_V1    2560
#define WS_KC    3072
#define WS_M     4096                      // M / P fp32 [2][512][512]
#define WS_PB    (WS_M + 2*DF*DF)          // P bf16 [2][512][512] (as ushort)
#define WS_QB    (WS_PB + DF*DF)           // Q bf16 [16384][512] (ushort); ALSO Gram partials earlier
#define WS_GP    WS_QB                     // Gp [4 chunks][2 cls][512][512] f32 = 8MB (consumed by k_asm before k_qinit overwrites)

typedef __attribute__((ext_vector_type(8))) short short8;
typedef __attribute__((ext_vector_type(4))) float floatx4;

__device__ __forceinline__ unsigned short f2bf(float f) {
    unsigned u = __float_as_uint(f);
    unsigned r = (u + 0x7fffu + ((u >> 16) & 1u)) >> 16;
    return (unsigned short)r;
}

__device__ __forceinline__ void load_lds16(const void* g, void* l) {
    __builtin_amdgcn_global_load_lds(
        (const __attribute__((address_space(1))) unsigned int*)g,
        (__attribute__((address_space(3))) unsigned int*)l, 16, 0, 0);
}

// ---------------- K1: class stats ----------------
__global__ __launch_bounds__(256) void k_stats(const float* __restrict__ S,
                                               const int* __restrict__ lab,
                                               float* __restrict__ ws) {
    __shared__ int lb[NS];
    __shared__ float r0[4][64], r1[4][64];
    __shared__ int rc[4];
    int tid = threadIdx.x;
    for (int l = tid; l < NS; l += 256) lb[l] = lab[l];
    __syncthreads();
    int dl = tid & 63, ch = tid >> 6;
    int dd = blockIdx.x * 64 + dl;
    float s0 = 0.f, s1 = 0.f;
    int n1 = 0;
    for (int n = ch * 128; n < ch * 128 + 128; ++n) {
        float v = S[n * DF + dd];
        if (lb[n]) { s1 += v; n1++; } else { s0 += v; }
    }
    r0[ch][dl] = s0; r1[ch][dl] = s1;
    if (dl == 0) rc[ch] = n1;
    __syncthreads();
    if (ch == 0) {
        float t0 = r0[0][dl] + r0[1][dl] + r0[2][dl] + r0[3][dl];
        float t1 = r1[0][dl] + r1[1][dl] + r1[2][dl] + r1[3][dl];
        int n1t = rc[0] + rc[1] + rc[2] + rc[3];
        float fn1 = (float)n1t, fn0 = (float)(NS - n1t);
        ws[WS_MEAN0 + dd] = t0 / fn0;
        ws[WS_MEAN1 + dd] = t1 / fn1;
        ws[WS_MEANA + dd] = (t0 + t1) / (float)NS;
        if (blockIdx.x == 0 && dl == 0) {
            ws[WS_CNT] = fn0; ws[WS_CNT + 1] = fn1;
            ws[WS_KC] = 0.f; ws[WS_KC + 1] = 0.f;
        }
    }
}

// ---------------- K2a: masked partial Grams (K-split x4) ----------------
__global__ __launch_bounds__(256) void k_gram_part(const float* __restrict__ S,
                                                   const int* __restrict__ lab,
                                                   float* __restrict__ ws) {
    __shared__ float SA[16 * 65];
    __shared__ float SB[16 * 65];
    __shared__ int lb[16];
    int tx = threadIdx.x, ty = threadIdx.y;
    int tid = ty * 16 + tx;
    int i0 = blockIdx.x * 64, j0 = blockIdx.y * 64;
    int z = blockIdx.z;
    float a0[4][4] = {{0.f}}, a1[4][4] = {{0.f}};
    for (int nc = z * 128; nc < z * 128 + 128; nc += 16) {
#pragma unroll
        for (int l = 0; l < 4; ++l) {
            int idx = tid + 256 * l;
            int nn = idx >> 6, col = idx & 63;
            SA[nn * 65 + col] = S[(nc + nn) * DF + i0 + col];
            SB[nn * 65 + col] = S[(nc + nn) * DF + j0 + col];
        }
        if (tid < 16) lb[tid] = lab[nc + tid];
        __syncthreads();
#pragma unroll
        for (int kk = 0; kk < 16; ++kk) {
            float av[4], bv[4];
#pragma unroll
            for (int r = 0; r < 4; ++r) av[r] = SA[kk * 65 + ty * 4 + r];
#pragma unroll
            for (int s = 0; s < 4; ++s) bv[s] = SB[kk * 65 + tx * 4 + s];
            if (lb[kk]) {
#pragma unroll
                for (int r = 0; r < 4; ++r)
#pragma unroll
                    for (int s = 0; s < 4; ++s) a1[r][s] += av[r] * bv[s];
            } else {
#pragma unroll
                for (int r = 0; r < 4; ++r)
#pragma unroll
                    for (int s = 0; s < 4; ++s) a0[r][s] += av[r] * bv[s];
            }
        }
        __syncthreads();
    }
    float* Gp = ws + WS_GP;
#pragma unroll
    for (int r = 0; r < 4; ++r) {
        int i = i0 + ty * 4 + r;
#pragma unroll
        for (int s = 0; s < 4; ++s) {
            int j = j0 + tx * 4 + s;
            Gp[((z * 2 + 0) * DF + i) * DF + j] = a0[r][s];
            Gp[((z * 2 + 1) * DF + i) * DF + j] = a1[r][s];
        }
    }
}

// ---------------- K2b: assemble M_c from partials ----------------
__global__ __launch_bounds__(256) void k_asm(float* __restrict__ ws) {
    const float* Gp = ws + WS_GP;
    int e = blockIdx.x * 256 + threadIdx.x;   // 0..262143
    int i = e >> 9, j = e & 511;
    float g0 = 0.f, g1 = 0.f;
#pragma unroll
    for (int ch = 0; ch < 4; ++ch) {
        g0 += Gp[((ch * 2 + 0) * DF + i) * DF + j];
        g1 += Gp[((ch * 2 + 1) * DF + i) * DF + j];
    }
    float n0 = ws[WS_CNT], n1 = ws[WS_CNT + 1];
    float lam0 = fminf(n0 / (n0 + 1.f), 0.1f);
    float lam1 = fminf(n1 / (n1 + 1.f), 0.1f);
    float m0i = ws[WS_MEAN0 + i], m1i = ws[WS_MEAN1 + i], mai = ws[WS_MEANA + i];
    float m0j = ws[WS_MEAN0 + j], m1j = ws[WS_MEAN1 + j], maj = ws[WS_MEANA + j];
    float task = (g0 + g1 - (float)NS * mai * maj) / (float)(NS - 1);
    float cov0 = (g0 - n0 * m0i * m0j) / (n0 - 1.f);
    float cov1 = (g1 - n1 * m1i * m1j) / (n1 - 1.f);
    float dg = (i == j) ? 0.1f : 0.f;
    ws[WS_M + i * DF + j] = lam0 * cov0 + (1.f - lam0) * task + dg;
    ws[WS_M + DF * DF + i * DF + j] = lam1 * cov1 + (1.f - lam1) * task + dg;
}

// ---------------- K3: fused Gauss-Jordan step, column-split phase-2 ----------------
// grid (64 tiles, 2 classes, 2 col-halves) = 256 blocks (1/CU, co-resident).
// Each block redundantly inverts the 64x64 pivot block in registers (fully
// unrolled, 1 barrier/pivot), then applies the col-half of its tile update.
__global__ __launch_bounds__(256) void k_step(float* __restrict__ ws, int k, int wbf) {
    int c = blockIdx.y;
    int jh = blockIdx.z;
    int ti = blockIdx.x >> 3, tj = blockIdx.x & 7;
    float* Mb = ws + WS_M + c * DF * DF;
    float* Akk = Mb + (k * 64) * DF + k * 64;
    unsigned short* pb = (unsigned short*)(ws + WS_PB) + (size_t)c * DF * DF;
    __shared__ float T[64 * 65];
    __shared__ float LV[64 * 65];
    __shared__ float LU[64 * 33];
    __shared__ float D1[64 * 33];
    __shared__ float rbuf[2][64];
    __shared__ float cbuf[2][64];
    int tid = threadIdx.x;
    int jl = tid & 63, w = tid >> 6;
    bool isdiag = (ti == k) && (tj == k);
    bool isrow = (ti == k) && (tj != k);
    bool iscol = (tj == k) && (ti != k);

    // phase 0: global reads (early, while all 256 blocks co-resident)
#pragma unroll
    for (int m = 0; m < 16; ++m) {
        int idx = tid + 256 * m;
        int i = idx >> 6, j = idx & 63;
        T[i * 65 + j] = Akk[i * DF + j];
    }
    if (ti != k) {
        const float* src = Mb + (ti * 64) * DF + k * 64;   // V = A[ti][k] (full)
#pragma unroll
        for (int m = 0; m < 16; ++m) {
            int idx = tid + 256 * m;
            int i = idx >> 6, j = idx & 63;
            LV[i * 65 + j] = src[i * DF + j];
        }
    }
    if (tj != k) {
        const float* src = Mb + (k * 64) * DF + tj * 64 + jh * 32;  // U half-cols
#pragma unroll
        for (int m = 0; m < 8; ++m) {
            int idx = tid + 256 * m;
            int i = idx >> 5, j = idx & 31;
            LU[i * 33 + j] = src[i * DF + j];
        }
    }
    __syncthreads();

    // phase 1: in-register GJ inversion of T (fully unrolled => VGPR-resident)
    float Tr[16];
#pragma unroll
    for (int m = 0; m < 16; ++m) Tr[m] = T[(w * 16 + m) * 65 + jl];
#pragma unroll
    for (int p = 0; p < 64; ++p) {
        const int par = p & 1;
        if (w == (p >> 4)) rbuf[par][jl] = Tr[p & 15];
        if (jl == p) {
#pragma unroll
            for (int m = 0; m < 16; ++m) cbuf[par][w * 16 + m] = Tr[m];
        }
        __syncthreads();
        float rv = rbuf[par][jl];
        float piv = 1.0f / rbuf[par][p];
        float rvp = rv * piv;
#pragma unroll
        for (int m = 0; m < 16; ++m) {
            int i = w * 16 + m;
            float cv = cbuf[par][i];
            float nv = Tr[m] - cv * rvp;
            if (i == p) nv = rvp;
            if (jl == p) nv = -cv * piv;
            if (i == p && jl == p) nv = piv;
            Tr[m] = nv;
        }
    }
#pragma unroll
    for (int m = 0; m < 16; ++m) T[(w * 16 + m) * 65 + jl] = Tr[m];
    __syncthreads();

    // phase 2: col-half tile update. thread: 2 rows x 4 cols of 64x32
    int tx8 = tid & 7, ty32 = tid >> 3;
    int cb0 = jh * 32;
    if (isdiag) {
#pragma unroll
        for (int m = 0; m < 8; ++m) {
            int idx = tid + 256 * m;
            int i = idx >> 5, j = idx & 31;
            float v = T[i * 65 + cb0 + j];
            Akk[i * DF + cb0 + j] = v;
            if (wbf) pb[(size_t)(k * 64 + i) * DF + k * 64 + cb0 + j] = f2bf(v);
        }
    } else if (isrow) {
        float acc[2][4] = {{0.f}};
        for (int kk = 0; kk < 64; ++kk) {
            float av[2], bv[4];
#pragma unroll
            for (int r = 0; r < 2; ++r) av[r] = T[(ty32 * 2 + r) * 65 + kk];
#pragma unroll
            for (int s = 0; s < 4; ++s) bv[s] = LU[kk * 33 + tx8 * 4 + s];
#pragma unroll
            for (int r = 0; r < 2; ++r)
#pragma unroll
                for (int s = 0; s < 4; ++s) acc[r][s] += av[r] * bv[s];
        }
        float* dst = Mb + (k * 64) * DF + tj * 64 + cb0;
#pragma unroll
        for (int r = 0; r < 2; ++r)
#pragma unroll
            for (int s = 0; s < 4; ++s) {
                float v = acc[r][s];
                dst[(ty32 * 2 + r) * DF + tx8 * 4 + s] = v;
                if (wbf) pb[(size_t)(k * 64 + ty32 * 2 + r) * DF + tj * 64 + cb0 + tx8 * 4 + s] = f2bf(v);
            }
    } else if (iscol) {
        float acc[2][4] = {{0.f}};
        for (int kk = 0; kk < 64; ++kk) {
            float av[2], bv[4];
#pragma unroll
            for (int r = 0; r < 2; ++r) av[r] = LV[(ty32 * 2 + r) * 65 + kk];
#pragma unroll
            for (int s = 0; s < 4; ++s) bv[s] = T[kk * 65 + cb0 + tx8 * 4 + s];
#pragma unroll
            for (int r = 0; r < 2; ++r)
#pragma unroll
                for (int s = 0; s < 4; ++s) acc[r][s] += av[r] * bv[s];
        }
        float* dst = Mb + (ti * 64) * DF + k * 64 + cb0;
#pragma unroll
        for (int r = 0; r < 2; ++r)
#pragma unroll
            for (int s = 0; s < 4; ++s) {
                float v = -acc[r][s];
                dst[(ty32 * 2 + r) * DF + tx8 * 4 + s] = v;
                if (wbf) pb[(size_t)(ti * 64 + ty32 * 2 + r) * DF + k * 64 + cb0 + tx8 * 4 + s] = f2bf(v);
            }
    } else {
        // D1 = P * U_half  (64x32)
        float a1[2][4] = {{0.f}};
        for (int kk = 0; kk < 64; ++kk) {
            float av[2], bv[4];
#pragma unroll
            for (int r = 0; r < 2; ++r) av[r] = T[(ty32 * 2 + r) * 65 + kk];
#pragma unroll
            for (int s = 0; s < 4; ++s) bv[s] = LU[kk * 33 + tx8 * 4 + s];
#pragma unroll
            for (int r = 0; r < 2; ++r)
#pragma unroll
                for (int s = 0; s < 4; ++s) a1[r][s] += av[r] * bv[s];
        }
        __syncthreads();
#pragma unroll
        for (int r = 0; r < 2; ++r)
#pragma unroll
            for (int s = 0; s < 4; ++s) D1[(ty32 * 2 + r) * 33 + tx8 * 4 + s] = a1[r][s];
        __syncthreads();
        // Y_half -= V * D1
        float a2[2][4] = {{0.f}};
        for (int kk = 0; kk < 64; ++kk) {
            float av[2], bv[4];
#pragma unroll
            for (int r = 0; r < 2; ++r) av[r] = LV[(ty32 * 2 + r) * 65 + kk];
#pragma unroll
            for (int s = 0; s < 4; ++s) bv[s] = D1[kk * 33 + tx8 * 4 + s];
#pragma unroll
            for (int r = 0; r < 2; ++r)
#pragma unroll
                for (int s = 0; s < 4; ++s) a2[r][s] += av[r] * bv[s];
        }
        float* dst = Mb + (ti * 64) * DF + tj * 64 + cb0;
#pragma unroll
        for (int r = 0; r < 2; ++r)
#pragma unroll
            for (int s = 0; s < 4; ++s) {
                int off = (ty32 * 2 + r) * DF + tx8 * 4 + s;
                float nv = dst[off] - a2[r][s];
                dst[off] = nv;
                if (wbf) pb[(size_t)(ti * 64 + ty32 * 2 + r) * DF + tj * 64 + cb0 + tx8 * 4 + s] = f2bf(nv);
            }
    }
}

// ---------------- K4: v_c = P_c m_c, k_c = m^T v ----------------
__global__ __launch_bounds__(256) void k_vk(float* __restrict__ ws) {
    int c = blockIdx.x >> 3, rb = blockIdx.x & 7;
    const float* P = ws + WS_M + c * DF * DF;
    const float* mc = ws + (c ? WS_MEAN1 : WS_MEAN0);
    float* v = ws + (c ? WS_V1 : WS_V0);
    __shared__ float ml[DF];
    __shared__ float red[4][64];
    int tid = threadIdx.x;
    for (int l = tid; l < DF; l += 256) ml[l] = mc[l];
    __syncthreads();
    int rl = tid & 63, ch = tid >> 6;
    int row = rb * 64 + rl;
    float dot = 0.f;
    const float* pr = P + (size_t)row * DF + ch * 128;
    for (int t = 0; t < 32; ++t) {
        float4 pv = *(const float4*)(pr + t * 4);
        const float* mm = ml + ch * 128 + t * 4;
        dot += pv.x * mm[0] + pv.y * mm[1] + pv.z * mm[2] + pv.w * mm[3];
    }
    red[ch][rl] = dot;
    __syncthreads();
    if (ch == 0) {
        float d = red[0][rl] + red[1][rl] + red[2][rl] + red[3][rl];
        v[row] = d;
        float kp = d * ml[row];
#pragma unroll
        for (int off = 32; off > 0; off >>= 1) kp += __shfl_down(kp, off);
        if (rl == 0) atomicAdd(&ws[WS_KC + c], kp);
    }
}

// ---------------- K5: fused Q->bf16 + logits init ----------------
__global__ __launch_bounds__(256) void k_qinit(const float* __restrict__ Q,
                                               float* __restrict__ ws,
                                               float* __restrict__ out) {
    unsigned short* qbw = (unsigned short*)(ws + WS_QB);
    const float* v0 = ws + WS_V0;
    const float* v1 = ws + WS_V1;
    int lane = threadIdx.x & 63;
    int q = blockIdx.x * 4 + (threadIdx.x >> 6);
    const float* qrow = Q + (size_t)q * DF + lane * 8;
    float4 x0 = *(const float4*)(qrow);
    float4 x1 = *(const float4*)(qrow + 4);
    const float* v0p = v0 + lane * 8;
    const float* v1p = v1 + lane * 8;
    float4 w00 = *(const float4*)(v0p), w01 = *(const float4*)(v0p + 4);
    float4 w10 = *(const float4*)(v1p), w11 = *(const float4*)(v1p + 4);
    float a0 = x0.x * w00.x + x0.y * w00.y + x0.z * w00.z + x0.w * w00.w
             + x1.x * w01.x + x1.y * w01.y + x1.z * w01.z + x1.w * w01.w;
    float a1 = x0.x * w10.x + x0.y * w10.y + x0.z * w10.z + x0.w * w10.w
             + x1.x * w11.x + x1.y * w11.y + x1.z * w11.z + x1.w * w11.w;
    short8 r;
    r[0] = (short)f2bf(x0.x); r[1] = (short)f2bf(x0.y);
    r[2] = (short)f2bf(x0.z); r[3] = (short)f2bf(x0.w);
    r[4] = (short)f2bf(x1.x); r[5] = (short)f2bf(x1.y);
    r[6] = (short)f2bf(x1.z); r[7] = (short)f2bf(x1.w);
    *(short8*)(qbw + (size_t)q * DF + lane * 8) = r;
#pragma unroll
    for (int off = 32; off > 0; off >>= 1) {
        a0 += __shfl_down(a0, off);
        a1 += __shfl_down(a1, off);
    }
    if (lane == 0) {
        out[q * 2 + 0] = 2.f * a0 - ws[WS_KC + 0];
        out[q * 2 + 1] = 2.f * a1 - ws[WS_KC + 1];
    }
}

// ---------------- K6: MFMA GEMM, m97-style LDS staging + swizzle ----------------
// 256x128 tile, BK=64. Staging: global_load_lds width=16, LDS dest =
// wave-uniform base + lane*16 (hard constraint). XOR swizzle: LDS[row][seg]
// holds global k-seg (seg ^ (row&7)) -> ds_read_b128 frag reads bank-even.
__global__ __launch_bounds__(256) void k_gemm(const float* __restrict__ ws,
                                              float* __restrict__ out) {
    const unsigned short* qb = (const unsigned short*)(ws + WS_QB);
    int c = blockIdx.y >> 2;
    int n0 = (blockIdx.y & 3) * 128;
    const unsigned short* pbc = (const unsigned short*)(ws + WS_PB) + (size_t)c * DF * DF;
    int q0 = blockIdx.x * 256;
    __shared__ __align__(16) unsigned short Abuf[256 * 64];   // 32 KB
    __shared__ __align__(16) unsigned short Bbuf[128 * 64];   // 16 KB
    int tid = threadIdx.x;
    int w = tid >> 6, lane = tid & 63;
    int quad = lane >> 4, l15 = lane & 15;
    floatx4 acc[4][8];
#pragma unroll
    for (int mt = 0; mt < 4; ++mt)
#pragma unroll
        for (int nt = 0; nt < 8; ++nt) acc[mt][nt] = (floatx4)(0.f);

    for (int kt = 0; kt < 8; ++kt) {
        int kc = kt * 64;
        // stage A (256 rows x 64 k): 8 issues of 256 lanes x 16B
#pragma unroll
        for (int i = 0; i < 8; ++i) {
            int o = tid * 16 + i * 4096;
            int row = o >> 7;
            int sg = ((o >> 4) & 7) ^ (row & 7);
            load_lds16(qb + (size_t)(q0 + row) * DF + kc + sg * 8, (char*)Abuf + o);
        }
        // stage B (128 rows x 64 k): 4 issues
#pragma unroll
        for (int i = 0; i < 4; ++i) {
            int o = tid * 16 + i * 4096;
            int row = o >> 7;
            int sg = ((o >> 4) & 7) ^ (row & 7);
            load_lds16(pbc + (size_t)(n0 + row) * DF + kc + sg * 8, (char*)Bbuf + o);
        }
        __syncthreads();   // drains vmcnt (global_load_lds) + lgkm
#pragma unroll
        for (int kk2 = 0; kk2 < 2; ++kk2) {
            int u = ((kk2 * 4 + quad) ^ (l15 & 7)) << 4;   // swizzled 16B seg offset
            short8 b[8];
#pragma unroll
            for (int nt = 0; nt < 8; ++nt)
                b[nt] = *(const short8*)((const char*)Bbuf + (nt * 16 + l15) * 128 + u);
#pragma unroll
            for (int mt = 0; mt < 4; ++mt) {
                short8 a = *(const short8*)((const char*)Abuf + (w * 64 + mt * 16 + l15) * 128 + u);
#pragma unroll
                for (int nt = 0; nt < 8; ++nt)
                    acc[mt][nt] = __builtin_amdgcn_mfma_f32_16x16x32_bf16(a, b[nt], acc[mt][nt], 0, 0, 0);
            }
        }
        __syncthreads();
    }
    // epilogue: partial row-dot with Q over this 128-col tile
#pragma unroll
    for (int mt = 0; mt < 4; ++mt)
#pragma unroll
        for (int reg = 0; reg < 4; ++reg) {
            int row = w * 64 + mt * 16 + quad * 4 + reg;
            float part = 0.f;
#pragma unroll
            for (int nt = 0; nt < 8; ++nt) {
                float h = acc[mt][nt][reg];
                unsigned qu = qb[(size_t)(q0 + row) * DF + n0 + nt * 16 + l15];
                part += h * __uint_as_float(qu << 16);
            }
            part += __shfl_xor(part, 1);
            part += __shfl_xor(part, 2);
            part += __shfl_xor(part, 4);
            part += __shfl_xor(part, 8);
            if (l15 == 0) atomicAdd(&out[(size_t)(q0 + row) * 2 + c], -part);
        }
}

extern "C" void kernel_launch(void* const* d_in, const int* in_sizes, int n_in,
                              void* d_out, int out_size, void* d_ws, size_t ws_size,
                              hipStream_t stream) {
    const float* S = (const float*)d_in[0];
    const int* lab = (const int*)d_in[1];
    const float* Q = (const float*)d_in[2];
    float* out = (float*)d_out;
    float* ws = (float*)d_ws;

    k_stats<<<8, 256, 0, stream>>>(S, lab, ws);
    k_gram_part<<<dim3(8, 8, 4), dim3(16, 16), 0, stream>>>(S, lab, ws);
    k_asm<<<1024, 256, 0, stream>>>(ws);
    for (int k = 0; k < 8; ++k)
        k_step<<<dim3(64, 2, 2), 256, 0, stream>>>(ws, k, k == 7 ? 1 : 0);
    k_vk<<<16, 256, 0, stream>>>(ws);
    k_qinit<<<NQ / 4, 256, 0, stream>>>(Q, ws, out);
    k_gemm<<<dim3(NQ / 256, 8), 256, 0, stream>>>(ws, out);
}

// Round 6
// 387.734 us; speedup vs baseline: 2.2280x; 1.0968x over previous
//
#include <hip/hip_runtime.h>

#define NS 512
#define DF 512
#define NQ 16384

// ws layout (float offsets)
#define WS_MEAN0 0
#define WS_MEAN1 512
#define WS_MEANA 1024
#define WS_CNT   1536
#define WS_V0    2048
#define WS_V1    2560
#define WS_KC    3072
#define WS_M     4096                      // M / P fp32 [2][512][512]
#define WS_PB    (WS_M + 2*DF*DF)          // P bf16 [2][512][512] (as ushort)
#define WS_QB    (WS_PB + DF*DF)           // Q bf16 [16384][512] (ushort); ALSO Gram partials earlier
#define WS_GP    WS_QB                     // Gp [8 chunks][2 cls][512][512] f32 = 16MB (consumed by k_asm before k_qinit overwrites)

typedef __attribute__((ext_vector_type(8))) short short8;
typedef __attribute__((ext_vector_type(4))) float floatx4;

__device__ __forceinline__ unsigned short f2bf(float f) {
    unsigned u = __float_as_uint(f);
    unsigned r = (u + 0x7fffu + ((u >> 16) & 1u)) >> 16;
    return (unsigned short)r;
}

// readlane for float: the raw builtin takes i32 -> passing float would
// VALUE-convert (truncate!). Bitcast explicitly. (R5 bug.)
__device__ __forceinline__ float readlane_f(float v, int lane) {
    return __uint_as_float(__builtin_amdgcn_readlane(__float_as_uint(v), lane));
}

__device__ __forceinline__ void load_lds16(const void* g, void* l) {
    __builtin_amdgcn_global_load_lds(
        (const __attribute__((address_space(1))) unsigned int*)g,
        (__attribute__((address_space(3))) unsigned int*)l, 16, 0, 0);
}

// ---------------- K1: class stats (8 blocks x 512 thr) ----------------
__global__ __launch_bounds__(512) void k_stats(const float* __restrict__ S,
                                               const int* __restrict__ lab,
                                               float* __restrict__ ws) {
    __shared__ int lb[NS];
    __shared__ float r0[8][64], r1[8][64];
    __shared__ int rc[8];
    int tid = threadIdx.x;
    for (int l = tid; l < NS; l += 512) lb[l] = lab[l];
    __syncthreads();
    int dl = tid & 63, ch = tid >> 6;          // ch 0..7
    int dd = blockIdx.x * 64 + dl;
    float s0 = 0.f, s1 = 0.f;
    int n1 = 0;
    for (int n = ch * 64; n < ch * 64 + 64; ++n) {
        float v = S[n * DF + dd];
        if (lb[n]) { s1 += v; n1++; } else { s0 += v; }
    }
    r0[ch][dl] = s0; r1[ch][dl] = s1;
    if (dl == 0) rc[ch] = n1;
    __syncthreads();
    if (ch == 0) {
        float t0 = 0.f, t1 = 0.f; int n1t = 0;
#pragma unroll
        for (int x = 0; x < 8; ++x) { t0 += r0[x][dl]; t1 += r1[x][dl]; n1t += rc[x]; }
        float fn1 = (float)n1t, fn0 = (float)(NS - n1t);
        ws[WS_MEAN0 + dd] = t0 / fn0;
        ws[WS_MEAN1 + dd] = t1 / fn1;
        ws[WS_MEANA + dd] = (t0 + t1) / (float)NS;
        if (blockIdx.x == 0 && dl == 0) {
            ws[WS_CNT] = fn0; ws[WS_CNT + 1] = fn1;
            ws[WS_KC] = 0.f; ws[WS_KC + 1] = 0.f;
        }
    }
}

// ---------------- K2a: masked partial Grams (K-split x8) ----------------
__global__ __launch_bounds__(256) void k_gram_part(const float* __restrict__ S,
                                                   const int* __restrict__ lab,
                                                   float* __restrict__ ws) {
    __shared__ float SA[16 * 65];
    __shared__ float SB[16 * 65];
    __shared__ int lb[16];
    int tx = threadIdx.x, ty = threadIdx.y;
    int tid = ty * 16 + tx;
    int i0 = blockIdx.x * 64, j0 = blockIdx.y * 64;
    int z = blockIdx.z;
    float a0[4][4] = {{0.f}}, a1[4][4] = {{0.f}};
    for (int nc = z * 64; nc < z * 64 + 64; nc += 16) {
#pragma unroll
        for (int l = 0; l < 4; ++l) {
            int idx = tid + 256 * l;
            int nn = idx >> 6, col = idx & 63;
            SA[nn * 65 + col] = S[(nc + nn) * DF + i0 + col];
            SB[nn * 65 + col] = S[(nc + nn) * DF + j0 + col];
        }
        if (tid < 16) lb[tid] = lab[nc + tid];
        __syncthreads();
#pragma unroll
        for (int kk = 0; kk < 16; ++kk) {
            float av[4], bv[4];
#pragma unroll
            for (int r = 0; r < 4; ++r) av[r] = SA[kk * 65 + ty * 4 + r];
#pragma unroll
            for (int s = 0; s < 4; ++s) bv[s] = SB[kk * 65 + tx * 4 + s];
            if (lb[kk]) {
#pragma unroll
                for (int r = 0; r < 4; ++r)
#pragma unroll
                    for (int s = 0; s < 4; ++s) a1[r][s] += av[r] * bv[s];
            } else {
#pragma unroll
                for (int r = 0; r < 4; ++r)
#pragma unroll
                    for (int s = 0; s < 4; ++s) a0[r][s] += av[r] * bv[s];
            }
        }
        __syncthreads();
    }
    float* Gp = ws + WS_GP;
#pragma unroll
    for (int r = 0; r < 4; ++r) {
        int i = i0 + ty * 4 + r;
#pragma unroll
        for (int s = 0; s < 4; ++s) {
            int j = j0 + tx * 4 + s;
            Gp[((z * 2 + 0) * DF + i) * DF + j] = a0[r][s];
            Gp[((z * 2 + 1) * DF + i) * DF + j] = a1[r][s];
        }
    }
}

// ---------------- K2b: assemble M_c from partials ----------------
__global__ __launch_bounds__(256) void k_asm(float* __restrict__ ws) {
    const float* Gp = ws + WS_GP;
    int e = blockIdx.x * 256 + threadIdx.x;   // 0..262143
    int i = e >> 9, j = e & 511;
    float g0 = 0.f, g1 = 0.f;
#pragma unroll
    for (int ch = 0; ch < 8; ++ch) {
        g0 += Gp[((ch * 2 + 0) * DF + i) * DF + j];
        g1 += Gp[((ch * 2 + 1) * DF + i) * DF + j];
    }
    float n0 = ws[WS_CNT], n1 = ws[WS_CNT + 1];
    float lam0 = fminf(n0 / (n0 + 1.f), 0.1f);
    float lam1 = fminf(n1 / (n1 + 1.f), 0.1f);
    float m0i = ws[WS_MEAN0 + i], m1i = ws[WS_MEAN1 + i], mai = ws[WS_MEANA + i];
    float m0j = ws[WS_MEAN0 + j], m1j = ws[WS_MEAN1 + j], maj = ws[WS_MEANA + j];
    float task = (g0 + g1 - (float)NS * mai * maj) / (float)(NS - 1);
    float cov0 = (g0 - n0 * m0i * m0j) / (n0 - 1.f);
    float cov1 = (g1 - n1 * m1i * m1j) / (n1 - 1.f);
    float dg = (i == j) ? 0.1f : 0.f;
    ws[WS_M + i * DF + j] = lam0 * cov0 + (1.f - lam0) * task + dg;
    ws[WS_M + DF * DF + i * DF + j] = lam1 * cov1 + (1.f - lam1) * task + dg;
}

// ---------------- K3: fused Gauss-Jordan step ----------------
// Phase 1 eliminates 4 pivots per barrier round (16 barriers, not 64):
// 4x4 pivot block inverted redundantly in registers (static indices),
// pivot rows broadcast via parity LDS, pivot columns via readlane_f (each
// wave owns its 16 rows -> column values are wave-uniform).
__global__ __launch_bounds__(256) void k_step(float* __restrict__ ws, int k, int wbf) {
    int c = blockIdx.y;
    int jh = blockIdx.z;
    int ti = blockIdx.x >> 3, tj = blockIdx.x & 7;
    float* Mb = ws + WS_M + c * DF * DF;
    float* Akk = Mb + (k * 64) * DF + k * 64;
    unsigned short* pb = (unsigned short*)(ws + WS_PB) + (size_t)c * DF * DF;
    __shared__ float T[64 * 65];
    __shared__ float LV[64 * 65];
    __shared__ float LU[64 * 33];
    __shared__ float D1[64 * 33];
    __shared__ float rbuf[2][4][64];
    int tid = threadIdx.x;
    int jl = tid & 63, w = tid >> 6;
    bool isdiag = (ti == k) && (tj == k);
    bool isrow = (ti == k) && (tj != k);
    bool iscol = (tj == k) && (ti != k);

    // phase 0: global reads (early, all 256 blocks co-resident)
#pragma unroll
    for (int m = 0; m < 16; ++m) {
        int idx = tid + 256 * m;
        int i = idx >> 6, j = idx & 63;
        T[i * 65 + j] = Akk[i * DF + j];
    }
    if (ti != k) {
        const float* src = Mb + (ti * 64) * DF + k * 64;   // V = A[ti][k] (full)
#pragma unroll
        for (int m = 0; m < 16; ++m) {
            int idx = tid + 256 * m;
            int i = idx >> 6, j = idx & 63;
            LV[i * 65 + j] = src[i * DF + j];
        }
    }
    if (tj != k) {
        const float* src = Mb + (k * 64) * DF + tj * 64 + jh * 32;  // U half-cols
#pragma unroll
        for (int m = 0; m < 8; ++m) {
            int idx = tid + 256 * m;
            int i = idx >> 5, j = idx & 31;
            LU[i * 33 + j] = src[i * DF + j];
        }
    }
    __syncthreads();

    // phase 1: in-register GJ inversion, 4 pivots per round
    float Tr[16];
#pragma unroll
    for (int m = 0; m < 16; ++m) Tr[m] = T[(w * 16 + m) * 65 + jl];
#pragma unroll
    for (int r = 0; r < 16; ++r) {
        const int q0 = r * 4;
        const int par = r & 1;
        if (w == (q0 >> 4)) {
            const int mb = q0 & 15;
            rbuf[par][0][jl] = Tr[mb + 0];
            rbuf[par][1][jl] = Tr[mb + 1];
            rbuf[par][2][jl] = Tr[mb + 2];
            rbuf[par][3][jl] = Tr[mb + 3];
        }
        __syncthreads();
        // 4x4 pivot block (wave-uniform values, broadcast LDS reads)
        float B[4][4];
#pragma unroll
        for (int a = 0; a < 4; ++a)
#pragma unroll
            for (int b = 0; b < 4; ++b) B[a][b] = rbuf[par][a][q0 + b];
        // invert B in place (GJ, no pivoting: SPD principal block)
#pragma unroll
        for (int p = 0; p < 4; ++p) {
            float piv = 1.0f / B[p][p];
#pragma unroll
            for (int j = 0; j < 4; ++j) if (j != p) B[p][j] *= piv;
#pragma unroll
            for (int i = 0; i < 4; ++i) if (i != p) {
                float f = B[i][p];
#pragma unroll
                for (int j = 0; j < 4; ++j) if (j != p) B[i][j] -= f * B[p][j];
                B[i][p] = -f * piv;
            }
            B[p][p] = piv;
        }
        // new pivot rows evaluated at this thread's column jl
        float r0v = rbuf[par][0][jl], r1v = rbuf[par][1][jl];
        float r2v = rbuf[par][2][jl], r3v = rbuf[par][3][jl];
        float nr[4];
#pragma unroll
        for (int a = 0; a < 4; ++a)
            nr[a] = B[a][0] * r0v + B[a][1] * r1v + B[a][2] * r2v + B[a][3] * r3v;
        // column-in-block selection (jl in [q0,q0+4))
        bool colin = ((jl >> 2) == r);
        int bsel = jl & 3;
        float Bc[4];
#pragma unroll
        for (int a = 0; a < 4; ++a)
            Bc[a] = bsel == 0 ? B[a][0]
                  : (bsel == 1 ? B[a][1] : (bsel == 2 ? B[a][2] : B[a][3]));
#pragma unroll
        for (int m = 0; m < 16; ++m) {
            float cv0 = readlane_f(Tr[m], q0 + 0);
            float cv1 = readlane_f(Tr[m], q0 + 1);
            float cv2 = readlane_f(Tr[m], q0 + 2);
            float cv3 = readlane_f(Tr[m], q0 + 3);
            float g = Tr[m] - (cv0 * nr[0] + cv1 * nr[1] + cv2 * nr[2] + cv3 * nr[3]);
            bool rowin = (((w * 16 + m) >> 2) == r);
            float gcol = -(cv0 * Bc[0] + cv1 * Bc[1] + cv2 * Bc[2] + cv3 * Bc[3]);
            if (rowin) g = nr[m & 3];
            if (colin) g = rowin ? Bc[m & 3] : gcol;
            Tr[m] = g;
        }
    }
#pragma unroll
    for (int m = 0; m < 16; ++m) T[(w * 16 + m) * 65 + jl] = Tr[m];
    __syncthreads();

    // phase 2: col-half tile update. thread: 2 rows x 4 cols of 64x32
    int tx8 = tid & 7, ty32 = tid >> 3;
    int cb0 = jh * 32;
    if (isdiag) {
#pragma unroll
        for (int m = 0; m < 8; ++m) {
            int idx = tid + 256 * m;
            int i = idx >> 5, j = idx & 31;
            float v = T[i * 65 + cb0 + j];
            Akk[i * DF + cb0 + j] = v;
            if (wbf) pb[(size_t)(k * 64 + i) * DF + k * 64 + cb0 + j] = f2bf(v);
        }
    } else if (isrow) {
        float acc[2][4] = {{0.f}};
        for (int kk = 0; kk < 64; ++kk) {
            float av[2], bv[4];
#pragma unroll
            for (int r = 0; r < 2; ++r) av[r] = T[(ty32 * 2 + r) * 65 + kk];
#pragma unroll
            for (int s = 0; s < 4; ++s) bv[s] = LU[kk * 33 + tx8 * 4 + s];
#pragma unroll
            for (int r = 0; r < 2; ++r)
#pragma unroll
                for (int s = 0; s < 4; ++s) acc[r][s] += av[r] * bv[s];
        }
        float* dst = Mb + (k * 64) * DF + tj * 64 + cb0;
#pragma unroll
        for (int r = 0; r < 2; ++r)
#pragma unroll
            for (int s = 0; s < 4; ++s) {
                float v = acc[r][s];
                dst[(ty32 * 2 + r) * DF + tx8 * 4 + s] = v;
                if (wbf) pb[(size_t)(k * 64 + ty32 * 2 + r) * DF + tj * 64 + cb0 + tx8 * 4 + s] = f2bf(v);
            }
    } else if (iscol) {
        float acc[2][4] = {{0.f}};
        for (int kk = 0; kk < 64; ++kk) {
            float av[2], bv[4];
#pragma unroll
            for (int r = 0; r < 2; ++r) av[r] = LV[(ty32 * 2 + r) * 65 + kk];
#pragma unroll
            for (int s = 0; s < 4; ++s) bv[s] = T[kk * 65 + cb0 + tx8 * 4 + s];
#pragma unroll
            for (int r = 0; r < 2; ++r)
#pragma unroll
                for (int s = 0; s < 4; ++s) acc[r][s] += av[r] * bv[s];
        }
        float* dst = Mb + (ti * 64) * DF + k * 64 + cb0;
#pragma unroll
        for (int r = 0; r < 2; ++r)
#pragma unroll
            for (int s = 0; s < 4; ++s) {
                float v = -acc[r][s];
                dst[(ty32 * 2 + r) * DF + tx8 * 4 + s] = v;
                if (wbf) pb[(size_t)(ti * 64 + ty32 * 2 + r) * DF + k * 64 + cb0 + tx8 * 4 + s] = f2bf(v);
            }
    } else {
        // D1 = P * U_half  (64x32)
        float a1[2][4] = {{0.f}};
        for (int kk = 0; kk < 64; ++kk) {
            float av[2], bv[4];
#pragma unroll
            for (int r = 0; r < 2; ++r) av[r] = T[(ty32 * 2 + r) * 65 + kk];
#pragma unroll
            for (int s = 0; s < 4; ++s) bv[s] = LU[kk * 33 + tx8 * 4 + s];
#pragma unroll
            for (int r = 0; r < 2; ++r)
#pragma unroll
                for (int s = 0; s < 4; ++s) a1[r][s] += av[r] * bv[s];
        }
        __syncthreads();
#pragma unroll
        for (int r = 0; r < 2; ++r)
#pragma unroll
            for (int s = 0; s < 4; ++s) D1[(ty32 * 2 + r) * 33 + tx8 * 4 + s] = a1[r][s];
        __syncthreads();
        // Y_half -= V * D1
        float a2[2][4] = {{0.f}};
        for (int kk = 0; kk < 64; ++kk) {
            float av[2], bv[4];
#pragma unroll
            for (int r = 0; r < 2; ++r) av[r] = LV[(ty32 * 2 + r) * 65 + kk];
#pragma unroll
            for (int s = 0; s < 4; ++s) bv[s] = D1[kk * 33 + tx8 * 4 + s];
#pragma unroll
            for (int r = 0; r < 2; ++r)
#pragma unroll
                for (int s = 0; s < 4; ++s) a2[r][s] += av[r] * bv[s];
        }
        float* dst = Mb + (ti * 64) * DF + tj * 64 + cb0;
#pragma unroll
        for (int r = 0; r < 2; ++r)
#pragma unroll
            for (int s = 0; s < 4; ++s) {
                int off = (ty32 * 2 + r) * DF + tx8 * 4 + s;
                float nv = dst[off] - a2[r][s];
                dst[off] = nv;
                if (wbf) pb[(size_t)(ti * 64 + ty32 * 2 + r) * DF + tj * 64 + cb0 + tx8 * 4 + s] = f2bf(nv);
            }
    }
}

// ---------------- K4: v_c = P_c m_c, k_c = m^T v ----------------
__global__ __launch_bounds__(256) void k_vk(float* __restrict__ ws) {
    int c = blockIdx.x >> 3, rb = blockIdx.x & 7;
    const float* P = ws + WS_M + c * DF * DF;
    const float* mc = ws + (c ? WS_MEAN1 : WS_MEAN0);
    float* v = ws + (c ? WS_V1 : WS_V0);
    __shared__ float ml[DF];
    __shared__ float red[4][64];
    int tid = threadIdx.x;
    for (int l = tid; l < DF; l += 256) ml[l] = mc[l];
    __syncthreads();
    int rl = tid & 63, ch = tid >> 6;
    int row = rb * 64 + rl;
    float dot = 0.f;
    const float* pr = P + (size_t)row * DF + ch * 128;
    for (int t = 0; t < 32; ++t) {
        float4 pv = *(const float4*)(pr + t * 4);
        const float* mm = ml + ch * 128 + t * 4;
        dot += pv.x * mm[0] + pv.y * mm[1] + pv.z * mm[2] + pv.w * mm[3];
    }
    red[ch][rl] = dot;
    __syncthreads();
    if (ch == 0) {
        float d = red[0][rl] + red[1][rl] + red[2][rl] + red[3][rl];
        v[row] = d;
        float kp = d * ml[row];
#pragma unroll
        for (int off = 32; off > 0; off >>= 1) kp += __shfl_down(kp, off);
        if (rl == 0) atomicAdd(&ws[WS_KC + c], kp);
    }
}

// ---------------- K5: fused Q->bf16 + logits init ----------------
__global__ __launch_bounds__(256) void k_qinit(const float* __restrict__ Q,
                                               float* __restrict__ ws,
                                               float* __restrict__ out) {
    unsigned short* qbw = (unsigned short*)(ws + WS_QB);
    const float* v0 = ws + WS_V0;
    const float* v1 = ws + WS_V1;
    int lane = threadIdx.x & 63;
    int q = blockIdx.x * 4 + (threadIdx.x >> 6);
    const float* qrow = Q + (size_t)q * DF + lane * 8;
    float4 x0 = *(const float4*)(qrow);
    float4 x1 = *(const float4*)(qrow + 4);
    const float* v0p = v0 + lane * 8;
    const float* v1p = v1 + lane * 8;
    float4 w00 = *(const float4*)(v0p), w01 = *(const float4*)(v0p + 4);
    float4 w10 = *(const float4*)(v1p), w11 = *(const float4*)(v1p + 4);
    float a0 = x0.x * w00.x + x0.y * w00.y + x0.z * w00.z + x0.w * w00.w
             + x1.x * w01.x + x1.y * w01.y + x1.z * w01.z + x1.w * w01.w;
    float a1 = x0.x * w10.x + x0.y * w10.y + x0.z * w10.z + x0.w * w10.w
             + x1.x * w11.x + x1.y * w11.y + x1.z * w11.z + x1.w * w11.w;
    short8 r;
    r[0] = (short)f2bf(x0.x); r[1] = (short)f2bf(x0.y);
    r[2] = (short)f2bf(x0.z); r[3] = (short)f2bf(x0.w);
    r[4] = (short)f2bf(x1.x); r[5] = (short)f2bf(x1.y);
    r[6] = (short)f2bf(x1.z); r[7] = (short)f2bf(x1.w);
    *(short8*)(qbw + (size_t)q * DF + lane * 8) = r;
#pragma unroll
    for (int off = 32; off > 0; off >>= 1) {
        a0 += __shfl_down(a0, off);
        a1 += __shfl_down(a1, off);
    }
    if (lane == 0) {
        out[q * 2 + 0] = 2.f * a0 - ws[WS_KC + 0];
        out[q * 2 + 1] = 2.f * a1 - ws[WS_KC + 1];
    }
}

// ---------------- K6: MFMA GEMM, 128x128 tile, LDS staging + swizzle ----------------
__global__ __launch_bounds__(256, 3) void k_gemm(const float* __restrict__ ws,
                                                 float* __restrict__ out) {
    const unsigned short* qb = (const unsigned short*)(ws + WS_QB);
    int c = blockIdx.y >> 2;
    int n0 = (blockIdx.y & 3) * 128;
    const unsigned short* pbc = (const unsigned short*)(ws + WS_PB) + (size_t)c * DF * DF;
    int q0 = blockIdx.x * 128;
    __shared__ __align__(16) unsigned short Abuf[128 * 64];   // 16 KB
    __shared__ __align__(16) unsigned short Bbuf[128 * 64];   // 16 KB
    int tid = threadIdx.x;
    int w = tid >> 6, lane = tid & 63;
    int quad = lane >> 4, l15 = lane & 15;
    floatx4 acc[2][8];
#pragma unroll
    for (int mt = 0; mt < 2; ++mt)
#pragma unroll
        for (int nt = 0; nt < 8; ++nt) acc[mt][nt] = (floatx4)(0.f);

    for (int kt = 0; kt < 8; ++kt) {
        int kc = kt * 64;
        // stage A (128 rows x 64 k): 4 issues of 256 lanes x 16B
#pragma unroll
        for (int i = 0; i < 4; ++i) {
            int o = tid * 16 + i * 4096;
            int row = o >> 7;
            int sg = ((o >> 4) & 7) ^ (row & 7);
            load_lds16(qb + (size_t)(q0 + row) * DF + kc + sg * 8, (char*)Abuf + o);
        }
        // stage B (128 rows x 64 k): 4 issues
#pragma unroll
        for (int i = 0; i < 4; ++i) {
            int o = tid * 16 + i * 4096;
            int row = o >> 7;
            int sg = ((o >> 4) & 7) ^ (row & 7);
            load_lds16(pbc + (size_t)(n0 + row) * DF + kc + sg * 8, (char*)Bbuf + o);
        }
        __syncthreads();
#pragma unroll
        for (int kk2 = 0; kk2 < 2; ++kk2) {
            int u = ((kk2 * 4 + quad) ^ (l15 & 7)) << 4;   // swizzled 16B seg offset
            short8 b[8];
#pragma unroll
            for (int nt = 0; nt < 8; ++nt)
                b[nt] = *(const short8*)((const char*)Bbuf + (nt * 16 + l15) * 128 + u);
#pragma unroll
            for (int mt = 0; mt < 2; ++mt) {
                short8 a = *(const short8*)((const char*)Abuf + (w * 32 + mt * 16 + l15) * 128 + u);
#pragma unroll
                for (int nt = 0; nt < 8; ++nt)
                    acc[mt][nt] = __builtin_amdgcn_mfma_f32_16x16x32_bf16(a, b[nt], acc[mt][nt], 0, 0, 0);
            }
        }
        __syncthreads();
    }
    // epilogue: partial row-dot with Q over this 128-col tile
#pragma unroll
    for (int mt = 0; mt < 2; ++mt)
#pragma unroll
        for (int reg = 0; reg < 4; ++reg) {
            int row = w * 32 + mt * 16 + quad * 4 + reg;
            float part = 0.f;
#pragma unroll
            for (int nt = 0; nt < 8; ++nt) {
                float h = acc[mt][nt][reg];
                unsigned qu = qb[(size_t)(q0 + row) * DF + n0 + nt * 16 + l15];
                part += h * __uint_as_float(qu << 16);
            }
            part += __shfl_xor(part, 1);
            part += __shfl_xor(part, 2);
            part += __shfl_xor(part, 4);
            part += __shfl_xor(part, 8);
            if (l15 == 0) atomicAdd(&out[(size_t)(q0 + row) * 2 + c], -part);
        }
}

extern "C" void kernel_launch(void* const* d_in, const int* in_sizes, int n_in,
                              void* d_out, int out_size, void* d_ws, size_t ws_size,
                              hipStream_t stream) {
    const float* S = (const float*)d_in[0];
    const int* lab = (const int*)d_in[1];
    const float* Q = (const float*)d_in[2];
    float* out = (float*)d_out;
    float* ws = (float*)d_ws;

    k_stats<<<8, 512, 0, stream>>>(S, lab, ws);
    k_gram_part<<<dim3(8, 8, 8), dim3(16, 16), 0, stream>>>(S, lab, ws);
    k_asm<<<1024, 256, 0, stream>>>(ws);
    for (int k = 0; k < 8; ++k)
        k_step<<<dim3(64, 2, 2), 256, 0, stream>>>(ws, k, k == 7 ? 1 : 0);
    k_vk<<<16, 256, 0, stream>>>(ws);
    k_qinit<<<NQ / 4, 256, 0, stream>>>(Q, ws, out);
    k_gemm<<<dim3(NQ / 128, 8), 256, 0, stream>>>(ws, out);
}